// Round 3
// baseline (11754.617 us; speedup 1.0000x reference)
//
#include <hip/hip_runtime.h>

// Problem constants
constexpr int V = 4000, E = 512, H = 512, NB = 32, To = 128, Ti = 512;
constexpr int T_STEPS = 129;          // To + 1

// ws layout (float offsets)
constexpr size_t OFF_XPRE = 0;                               // [129][32][2048]
constexpr size_t OFF_WP0  = OFF_XPRE + (size_t)129*32*2048;  // [256][1024][8]
constexpr size_t OFF_WP1  = OFF_WP0 + (size_t)256*1024*8;
constexpr size_t OFF_H0   = OFF_WP1 + (size_t)256*1024*8;    // [2][512][32]
constexpr size_t OFF_C0   = OFF_H0 + 2*512*32;               // [512][32]
constexpr size_t OFF_C1   = OFF_C0 + 512*32;
constexpr size_t OFF_H1A  = OFF_C1 + 512*32;                 // [130][512][32]
constexpr size_t OFF_ATTC = OFF_H1A + (size_t)130*512*32;    // [130][512][32]
constexpr size_t OFF_H1T  = OFF_ATTC + (size_t)130*512*32;   // [32][520] transposed h1(t+1)
constexpr size_t OFF_HID  = OFF_H1T + (size_t)32*520;        // [4128][512]
constexpr size_t OFF_PM   = OFF_HID + (size_t)4128*512;      // [256]
constexpr size_t OFF_PS   = OFF_PM + 256;                    // [256]
constexpr size_t OFF_PCTX = OFF_PS + 256;                    // [256][512]
constexpr size_t OFF_CPM  = OFF_PCTX + (size_t)256*512;      // [4128][16]
constexpr size_t OFF_CPS  = OFF_CPM + (size_t)4128*16;
constexpr size_t OFF_TGT  = OFF_CPS + (size_t)4128*16;       // [4128]
constexpr size_t OFF_FLAGS= OFF_TGT + 4128;                  // [256] per-block epoch flags

__device__ __forceinline__ float sigmf(float x) { return 1.0f / (1.0f + __expf(-x)); }
__device__ __forceinline__ float bfl(unsigned u) { return __uint_as_float(u << 16); }
__device__ __forceinline__ float bfh(unsigned u) { return __uint_as_float(u & 0xffff0000u); }
__device__ __forceinline__ unsigned short f2b(float x) {
    unsigned u = __float_as_uint(x);
    unsigned r = (u + 0x7fffu + ((u >> 16) & 1u)) >> 16;
    return (unsigned short)r;
}

// Contention-free grid barrier: per-block epoch flag (release store),
// parallel poll (one flag per thread), then agent acquire fence.
__device__ __forceinline__ void gbar(unsigned* flags, int b, int tid, unsigned& epoch) {
    ++epoch;
    __syncthreads();
    if (tid == 0)
        __hip_atomic_store(flags + b, epoch, __ATOMIC_RELEASE, __HIP_MEMORY_SCOPE_AGENT);
    while (__hip_atomic_load(flags + tid, __ATOMIC_RELAXED, __HIP_MEMORY_SCOPE_AGENT) < epoch)
        __builtin_amdgcn_s_sleep(1);
    __builtin_amdgcn_fence(__ATOMIC_ACQUIRE, "agent");
    __syncthreads();
}

// ---------------- init: zero state buffers + barrier flags ----------------
__global__ __launch_bounds__(256) void k_init(float* ws) {
    int id = blockIdx.x * 256 + threadIdx.x;   // 0..82175
    if (id < 81920) {
        int reg = id / 16384, off = id % 16384;
        size_t base;
        switch (reg) {
            case 0: base = OFF_H0; break;          // h0 ping buf 0
            case 1: base = OFF_C0; break;
            case 2: base = OFF_C1; break;
            case 3: base = OFF_H1A; break;         // h1_all slab 0
            default: base = OFF_ATTC; break;       // attc_all slab 0
        }
        ws[base + off] = 0.0f;
    } else {
        ws[OFF_FLAGS + (id - 81920)] = 0.0f;       // bit-zero == unsigned 0
    }
}

// ---------------- weight pre-pack for the recurrent skinny GEMMs ----------------
// Wp[b][k][r], b=0..255 owns 8 g-rows: gRow = (r>>1)*512 + b*2 + (r&1)
__global__ __launch_bounds__(256) void k_pack0(const float* __restrict__ W_ih0,
                                               const float* __restrict__ W_hh0,
                                               float* __restrict__ Wp) {
    int p = blockIdx.x * 256 + threadIdx.x;    // 0..2097151
    int r = p & 7, k = (p >> 3) & 1023, b = p >> 13;
    int gRow = ((r >> 1) & 3) * 512 + b * 2 + (r & 1);
    float v = (k < 512) ? W_ih0[(size_t)gRow * 1024 + 512 + k]
                        : W_hh0[(size_t)gRow * 512 + (k - 512)];
    Wp[p] = v;
}
__global__ __launch_bounds__(256) void k_pack1(const float* __restrict__ W_ih1,
                                               const float* __restrict__ W_hh1,
                                               float* __restrict__ Wp) {
    int p = blockIdx.x * 256 + threadIdx.x;
    int r = p & 7, k = (p >> 3) & 1023, b = p >> 13;
    int gRow = ((r >> 1) & 3) * 512 + b * 2 + (r & 1);
    float v = (k < 512) ? W_ih1[(size_t)gRow * 512 + k]
                        : W_hh1[(size_t)gRow * 512 + (k - 512)];
    Wp[p] = v;
}

// ---------------- X_pre GEMM: [4128][2048] = emb_rows @ W_ih0[:, :512].T + biases ----------------
__global__ __launch_bounds__(256) void k_xpre(const int* __restrict__ padded,
                                              const float* __restrict__ embedding,
                                              const float* __restrict__ W_ih0,
                                              const float* __restrict__ b_ih0,
                                              const float* __restrict__ b_hh0,
                                              float* __restrict__ Xpre) {
    __shared__ __align__(16) float At[32 * 33];
    __shared__ __align__(16) float Bt[32 * 68];
    __shared__ int toks[32];
    const int t = blockIdx.x, j0 = blockIdx.y * 64, tid = threadIdx.x;
    if (tid < 32) toks[tid] = (t == 0) ? 1 : padded[tid * 128 + (t - 1)];
    __syncthreads();
    const int ty = tid >> 4, tx = tid & 15;
    float acc[8];
#pragma unroll
    for (int i = 0; i < 8; ++i) acc[i] = 0.0f;
    for (int k0 = 0; k0 < 512; k0 += 32) {
        __syncthreads();
        {
            int r = tid >> 3, kk4 = tid & 7;
            float4 v = *(const float4*)(embedding + (size_t)toks[r] * 512 + k0 + kk4 * 4);
            At[(kk4 * 4 + 0) * 33 + r] = v.x;
            At[(kk4 * 4 + 1) * 33 + r] = v.y;
            At[(kk4 * 4 + 2) * 33 + r] = v.z;
            At[(kk4 * 4 + 3) * 33 + r] = v.w;
#pragma unroll
            for (int i2 = 0; i2 < 2; ++i2) {
                int f = tid + 256 * i2;
                int j = f >> 3, kb = f & 7;
                float4 w = *(const float4*)(W_ih0 + (size_t)(j0 + j) * 1024 + k0 + kb * 4);
                Bt[(kb * 4 + 0) * 68 + j] = w.x;
                Bt[(kb * 4 + 1) * 68 + j] = w.y;
                Bt[(kb * 4 + 2) * 68 + j] = w.z;
                Bt[(kb * 4 + 3) * 68 + j] = w.w;
            }
        }
        __syncthreads();
#pragma unroll
        for (int kk = 0; kk < 32; ++kk) {
            float a0 = At[kk * 33 + ty], a1 = At[kk * 33 + ty + 16];
            float4 b4 = *(const float4*)&Bt[kk * 68 + tx * 4];
            acc[0] += a0 * b4.x; acc[1] += a0 * b4.y; acc[2] += a0 * b4.z; acc[3] += a0 * b4.w;
            acc[4] += a1 * b4.x; acc[5] += a1 * b4.y; acc[6] += a1 * b4.z; acc[7] += a1 * b4.w;
        }
    }
    int j = j0 + tx * 4;
    float4 bi = *(const float4*)(b_ih0 + j);
    float4 bh = *(const float4*)(b_hh0 + j);
    int r0 = t * 32;
    float4 o0 = {acc[0] + bi.x + bh.x, acc[1] + bi.y + bh.y, acc[2] + bi.z + bh.z, acc[3] + bi.w + bh.w};
    float4 o1 = {acc[4] + bi.x + bh.x, acc[5] + bi.y + bh.y, acc[6] + bi.z + bh.z, acc[7] + bi.w + bh.w};
    *(float4*)(Xpre + (size_t)(r0 + ty) * 2048 + j) = o0;
    *(float4*)(Xpre + (size_t)(r0 + ty + 16) * 2048 + j) = o1;
}

// ---------------- LSTM phase: weights in LDS, x direct from global (coalesced broadcast) ----------------
// Block owns 8 g-rows (4 gates x 2 h-cols). Thread (q=tid>>5, kq=tid&31):
// outer product 8 rows x 4 samples; x loads are fully coalesced 1KB/wave-instr.
__device__ __forceinline__ void lstm_phase(
    const float* __restrict__ lds_wp,    // [1024][8] this pack, in LDS
    const float* __restrict__ srcA,      // K 0..511 source, [k][32] global
    const float* __restrict__ srcB,      // K 512..1023 source, [k][32] global
    const float* __restrict__ xpre_row,  // Xpre + t*32*2048, or nullptr
    const float* __restrict__ bia, const float* __restrict__ bib,
    float* __restrict__ cT, float* __restrict__ hOut, float* __restrict__ hT,
    int b, int tid, int q, int kq, float* red, float* gv) {
    float acc[8][4];
#pragma unroll
    for (int r = 0; r < 8; ++r)
#pragma unroll
        for (int s = 0; s < 4; ++s) acc[r][s] = 0.0f;

#pragma unroll
    for (int tt = 0; tt < 8; ++tt) {
        const float* src = (tt < 4) ? (srcA + tt * 4096) : (srcB + (tt - 4) * 4096);
#pragma unroll
        for (int i = 0; i < 4; ++i) {
            int lk = kq + 32 * i;
            float4 x4 = *(const float4*)(src + (size_t)lk * 32 + (q << 2));
            const float* wp = lds_wp + (size_t)(tt * 128 + lk) * 8;
            float4 wA = *(const float4*)(wp);
            float4 wB = *(const float4*)(wp + 4);
            acc[0][0] += wA.x * x4.x; acc[0][1] += wA.x * x4.y; acc[0][2] += wA.x * x4.z; acc[0][3] += wA.x * x4.w;
            acc[1][0] += wA.y * x4.x; acc[1][1] += wA.y * x4.y; acc[1][2] += wA.y * x4.z; acc[1][3] += wA.y * x4.w;
            acc[2][0] += wA.z * x4.x; acc[2][1] += wA.z * x4.y; acc[2][2] += wA.z * x4.z; acc[2][3] += wA.z * x4.w;
            acc[3][0] += wA.w * x4.x; acc[3][1] += wA.w * x4.y; acc[3][2] += wA.w * x4.z; acc[3][3] += wA.w * x4.w;
            acc[4][0] += wB.x * x4.x; acc[4][1] += wB.x * x4.y; acc[4][2] += wB.x * x4.z; acc[4][3] += wB.x * x4.w;
            acc[5][0] += wB.y * x4.x; acc[5][1] += wB.y * x4.y; acc[5][2] += wB.y * x4.z; acc[5][3] += wB.y * x4.w;
            acc[6][0] += wB.z * x4.x; acc[6][1] += wB.z * x4.y; acc[6][2] += wB.z * x4.z; acc[6][3] += wB.z * x4.w;
            acc[7][0] += wB.w * x4.x; acc[7][1] += wB.w * x4.y; acc[7][2] += wB.w * x4.z; acc[7][3] += wB.w * x4.w;
        }
    }
    // cross-kq reduction, 2 chunks of 4 rows: layout [n][r*33+kq] (writes conflict-free)
#pragma unroll
    for (int c = 0; c < 2; ++c) {
        __syncthreads();
#pragma unroll
        for (int r = 0; r < 4; ++r)
#pragma unroll
            for (int s = 0; s < 4; ++s)
                red[(q * 4 + s) * 132 + r * 33 + kq] = acc[c * 4 + r][s];
        __syncthreads();
        if (tid < 128) {
            int rr = tid >> 5, n = tid & 31;
            float g = 0.0f;
#pragma unroll
            for (int k2 = 0; k2 < 32; ++k2) g += red[n * 132 + rr * 33 + k2];
            gv[(c * 4 + rr) * 33 + n] = g;
        }
    }
    __syncthreads();
    if (tid < 64) {
        int jl = tid >> 5, nn = tid & 31;
        float gi = gv[(0 + jl) * 33 + nn];
        float gf = gv[(2 + jl) * 33 + nn];
        float gg = gv[(4 + jl) * 33 + nn];
        float go = gv[(6 + jl) * 33 + nn];
        int j = b * 2 + jl;
        if (xpre_row) {
            const float* xp = xpre_row + (size_t)nn * 2048;
            gi += xp[j]; gf += xp[512 + j]; gg += xp[1024 + j]; go += xp[1536 + j];
        } else {
            gi += bia[j] + bib[j];
            gf += bia[512 + j] + bib[512 + j];
            gg += bia[1024 + j] + bib[1024 + j];
            go += bia[1536 + j] + bib[1536 + j];
        }
        float c = cT[j * 32 + nn];
        float cn = sigmf(gf) * c + sigmf(gi) * tanhf(gg);
        float hn = sigmf(go) * tanhf(cn);
        cT[j * 32 + nn] = cn;
        hOut[j * 32 + nn] = hn;
        if (hT) hT[(size_t)nn * 520 + j] = hn;
    }
}

// ---------------- cooperative sequential kernel ----------------
__global__ __launch_bounds__(256, 1) void k_seq(float* ws,
                                                const float* __restrict__ enc,
                                                const float* __restrict__ b_ih1,
                                                const float* __restrict__ b_hh1) {
    __shared__ __align__(16) float lds_w[16384];            // 64 KB: both weight packs
    __shared__ __align__(16) float red[4224];               // 16.9 KB: reduction / attn scratch
    __shared__ __align__(16) float gv[264];                 // gate sums
    __shared__ __align__(16) unsigned short lds_e[35328];   // 69 KB: enc slice bf16 [64] rows, skewed

    const int b = blockIdx.x, tid = threadIdx.x;
    const int q = tid >> 5, kq = tid & 31;

    float* Xpre = ws + OFF_XPRE;
    float* h0   = ws + OFF_H0;
    float* c0   = ws + OFF_C0;
    float* c1   = ws + OFF_C1;
    float* h1a  = ws + OFF_H1A;
    float* attc = ws + OFF_ATTC;
    float* h1T  = ws + OFF_H1T;
    float* pm   = ws + OFF_PM;
    float* ps   = ws + OFF_PS;
    float* pctx = ws + OFF_PCTX;
    unsigned* flags = (unsigned*)(ws + OFF_FLAGS);
    unsigned epoch = 0;

    // ---- one-time LDS residency: weight packs (fp32) + enc slice (bf16, skewed layout) ----
    {
        const float4* w0 = (const float4*)(ws + OFF_WP0 + (size_t)b * 8192);
        const float4* w1 = (const float4*)(ws + OFF_WP1 + (size_t)b * 8192);
        for (int f = tid; f < 2048; f += 256) ((float4*)lds_w)[f] = w0[f];
        for (int f = tid; f < 2048; f += 256) ((float4*)(lds_w + 8192))[f] = w1[f];
        const int n = b >> 3, ts0 = (b & 7) * 64;
        const float4* encn = (const float4*)(enc + ((size_t)n * 512 + ts0) * 512);
#pragma unroll 4
        for (int j = 0; j < 32; ++j) {
            int f = tid + j * 256;              // 0..8191 float4 of [64][512]
            int row = f >> 7, c4 = f & 127;
            float4 v = encn[(size_t)row * 128 + c4];
            ushort4 o;
            o.x = f2b(v.x); o.y = f2b(v.y); o.z = f2b(v.z); o.w = f2b(v.w);
            // skewed: row*552 + chunk*136 + within-chunk
            *(ushort4*)(lds_e + (size_t)row * 552 + (c4 >> 5) * 136 + (c4 & 31) * 4) = o;
        }
    }
    __syncthreads();

    for (int t = 0; t < T_STEPS; ++t) {
        const int rd0 = t & 1, wr0 = rd0 ^ 1;
        // ---- P1: LSTM0 : x = [attc(t), h0(t-1)] ----
        lstm_phase(lds_w, attc + (size_t)t * 16384, h0 + (size_t)rd0 * 16384,
                   Xpre + (size_t)t * 32 * 2048, nullptr, nullptr,
                   c0, h0 + (size_t)wr0 * 16384, nullptr, b, tid, q, kq, red, gv);
        gbar(flags, b, tid, epoch);
        // ---- P2: LSTM1 : x = [h0(t), h1(t-1)] ----
        lstm_phase(lds_w + 8192, h0 + (size_t)wr0 * 16384, h1a + (size_t)t * 16384,
                   nullptr, b_ih1, b_hh1,
                   c1, h1a + (size_t)(t + 1) * 16384, h1T, b, tid, q, kq, red, gv);
        gbar(flags, b, tid, epoch);
        // ---- P3a: attention partial (8 blocks per sample, 64 frames each, enc in LDS) ----
        {
            const int n = b >> 3;
            float* h_l = red;          // 512
            float* scp = red + 512;    // 256
            float* p_l = red + 768;    // 64
            {   // coalesced h load from transposed copy
                float2 hv = *(const float2*)(h1T + (size_t)n * 520 + tid * 2);
                *(float2*)(h_l + tid * 2) = hv;
            }
            __syncthreads();
            {
                int ti = tid >> 2, kp = tid & 3;
                const unsigned short* er = lds_e + (size_t)ti * 552 + kp * 136;
                const float* hr = h_l + kp * 128;
                float s = 0.0f;
#pragma unroll
                for (int k8 = 0; k8 < 16; ++k8) {
                    uint4 u = *(const uint4*)(er + k8 * 8);
                    const float* h8 = hr + k8 * 8;
                    s += bfl(u.x) * h8[0] + bfh(u.x) * h8[1]
                       + bfl(u.y) * h8[2] + bfh(u.y) * h8[3]
                       + bfl(u.z) * h8[4] + bfh(u.z) * h8[5]
                       + bfl(u.w) * h8[6] + bfh(u.w) * h8[7];
                }
                scp[kp * 64 + ti] = s;
            }
            __syncthreads();
            if (tid < 64) {
                float sc = scp[tid] + scp[64 + tid] + scp[128 + tid] + scp[192 + tid];
                float m = sc;
                for (int o = 32; o; o >>= 1) m = fmaxf(m, __shfl_xor(m, o));
                float e = __expf(sc - m);
                float z = e;
                for (int o = 32; o; o >>= 1) z += __shfl_xor(z, o);
                p_l[tid] = e;
                if (tid == 0) { pm[b] = m; ps[b] = z; }
            }
            __syncthreads();
            {
                int f0 = tid * 2;
                const unsigned short* eb = lds_e + (f0 >> 7) * 136 + (f0 & 127);
                float cv0 = 0.0f, cv1 = 0.0f;
#pragma unroll 8
                for (int ti = 0; ti < 64; ++ti) {
                    float w = p_l[ti];
                    unsigned u = *(const unsigned*)(eb + (size_t)ti * 552);
                    cv0 += w * bfl(u); cv1 += w * bfh(u);
                }
                float2 o2 = {cv0, cv1};
                *(float2*)&pctx[(size_t)b * 512 + f0] = o2;
            }
        }
        gbar(flags, b, tid, epoch);
        // ---- P3b: combine softmax partials -> attc(t+1) ----
        if (b < 64) {
            int n = b >> 1, kh = (b & 1) * 256;
            int k = kh + tid;
            float M = -1e30f;
#pragma unroll
            for (int c = 0; c < 8; ++c) M = fmaxf(M, pm[n * 8 + c]);
            float Z = 0.0f, ctxv = 0.0f;
#pragma unroll
            for (int c = 0; c < 8; ++c) {
                float scl = __expf(pm[n * 8 + c] - M);
                Z += ps[n * 8 + c] * scl;
                ctxv += pctx[(size_t)(n * 8 + c) * 512 + k] * scl;
            }
            attc[(size_t)(t + 1) * 16384 + (size_t)k * 32 + n] = ctxv / Z;
        }
        gbar(flags, b, tid, epoch);
    }
}

// ---------------- MLP hidden GEMM: hidden[4128][512] = tanh([h1,attc] @ W1.T + b1) ----------------
__global__ __launch_bounds__(256) void k_mlp(const float* __restrict__ h1a,
                                             const float* __restrict__ attc,
                                             const float* __restrict__ W1,
                                             const float* __restrict__ b1,
                                             float* __restrict__ hidden) {
    __shared__ __align__(16) float At[32 * 33];
    __shared__ __align__(16) float Bt[32 * 68];
    const int t = blockIdx.x, j0 = blockIdx.y * 64, tid = threadIdx.x;
    const int ty = tid >> 4, tx = tid & 15;
    float acc[8];
#pragma unroll
    for (int i = 0; i < 8; ++i) acc[i] = 0.0f;
    for (int k0 = 0; k0 < 1024; k0 += 32) {
        const float* src = (k0 < 512) ? (h1a + (size_t)(t + 1) * 16384 + (size_t)k0 * 32)
                                      : (attc + (size_t)(t + 1) * 16384 + (size_t)(k0 - 512) * 32);
        __syncthreads();
        {
            int kk = tid >> 3, n4 = tid & 7;
            float4 v = *(const float4*)(src + (size_t)kk * 32 + n4 * 4);
            At[kk * 33 + n4 * 4 + 0] = v.x;
            At[kk * 33 + n4 * 4 + 1] = v.y;
            At[kk * 33 + n4 * 4 + 2] = v.z;
            At[kk * 33 + n4 * 4 + 3] = v.w;
#pragma unroll
            for (int i2 = 0; i2 < 2; ++i2) {
                int f = tid + 256 * i2;
                int j = f >> 3, kb = f & 7;
                float4 w = *(const float4*)(W1 + (size_t)(j0 + j) * 1024 + k0 + kb * 4);
                Bt[(kb * 4 + 0) * 68 + j] = w.x;
                Bt[(kb * 4 + 1) * 68 + j] = w.y;
                Bt[(kb * 4 + 2) * 68 + j] = w.z;
                Bt[(kb * 4 + 3) * 68 + j] = w.w;
            }
        }
        __syncthreads();
#pragma unroll
        for (int kk = 0; kk < 32; ++kk) {
            float a0 = At[kk * 33 + ty], a1 = At[kk * 33 + ty + 16];
            float4 b4 = *(const float4*)&Bt[kk * 68 + tx * 4];
            acc[0] += a0 * b4.x; acc[1] += a0 * b4.y; acc[2] += a0 * b4.z; acc[3] += a0 * b4.w;
            acc[4] += a1 * b4.x; acc[5] += a1 * b4.y; acc[6] += a1 * b4.z; acc[7] += a1 * b4.w;
        }
    }
    int j = j0 + tx * 4;
    float4 bv = *(const float4*)(b1 + j);
    int r0 = t * 32;
    float4 o0 = {tanhf(acc[0] + bv.x), tanhf(acc[1] + bv.y), tanhf(acc[2] + bv.z), tanhf(acc[3] + bv.w)};
    float4 o1 = {tanhf(acc[4] + bv.x), tanhf(acc[5] + bv.y), tanhf(acc[6] + bv.z), tanhf(acc[7] + bv.w)};
    *(float4*)(hidden + (size_t)(r0 + ty) * 512 + j) = o0;
    *(float4*)(hidden + (size_t)(r0 + ty + 16) * 512 + j) = o1;
}

// ---------------- fused logits + chunk logsumexp ----------------
__global__ __launch_bounds__(256) void k_ce(const float* __restrict__ hidden,
                                            const float* __restrict__ W2,
                                            const float* __restrict__ b2,
                                            const int* __restrict__ padded,
                                            float* __restrict__ cpm, float* __restrict__ cps,
                                            float* __restrict__ tgt) {
    __shared__ __align__(16) float lg[256 * 33];
    __shared__ float mred[8 * 32];
    __shared__ float Mf[32];
    __shared__ float sred[8 * 32];
    const int t = blockIdx.x, vc = blockIdx.y, tid = threadIdx.x;
    const int v = vc * 256 + tid;
    const float* hrow = hidden + (size_t)t * 32 * 512;
    if (v < V) {
        float acc[32];
#pragma unroll
        for (int n = 0; n < 32; ++n) acc[n] = 0.0f;
        const float* w = W2 + (size_t)v * 512;
        for (int k4 = 0; k4 < 128; ++k4) {
            float4 a = *(const float4*)(w + k4 * 4);
#pragma unroll
            for (int n = 0; n < 32; ++n) {
                float4 h = *(const float4*)(hrow + (size_t)n * 512 + k4 * 4);
                acc[n] += a.x * h.x + a.y * h.y + a.z * h.z + a.w * h.w;
            }
        }
        float bb = b2[v];
#pragma unroll
        for (int n = 0; n < 32; ++n) lg[tid * 33 + n] = acc[n] + bb;
    } else {
#pragma unroll
        for (int n = 0; n < 32; ++n) lg[tid * 33 + n] = -1e30f;
    }
    __syncthreads();
    {
        int n = tid & 31, c = tid >> 5;
        float m = -1e30f;
        for (int i = 0; i < 32; ++i) m = fmaxf(m, lg[(c * 32 + i) * 33 + n]);
        mred[c * 32 + n] = m;
    }
    __syncthreads();
    if (tid < 32) {
        float M = mred[tid];
#pragma unroll
        for (int c = 1; c < 8; ++c) M = fmaxf(M, mred[c * 32 + tid]);
        Mf[tid] = M;
    }
    __syncthreads();
    {
        int n = tid & 31, c = tid >> 5;
        float M = Mf[n], s = 0.0f;
        for (int i = 0; i < 32; ++i) s += __expf(lg[(c * 32 + i) * 33 + n] - M);
        sred[c * 32 + n] = s;
    }
    __syncthreads();
    if (tid < 32) {
        int n = tid;
        float S = 0.0f;
#pragma unroll
        for (int c = 0; c < 8; ++c) S += sred[c * 32 + n];
        int r = t * 32 + n;
        cpm[(size_t)r * 16 + vc] = Mf[n];
        cps[(size_t)r * 16 + vc] = S;
        int vstar = (t < 128) ? padded[n * 128 + t] : 2;
        int vl = vstar - vc * 256;
        if (vl >= 0 && vl < 256) tgt[r] = lg[vl * 33 + n];
    }
}

// ---------------- final combine + CE reduction ----------------
__global__ __launch_bounds__(256) void k_final(const float* __restrict__ cpm,
                                               const float* __restrict__ cps,
                                               const float* __restrict__ tgt,
                                               float* __restrict__ out) {
    __shared__ float red[256];
    float local = 0.0f;
    for (int r = threadIdx.x; r < 4128; r += 256) {
        float M = -1e30f;
#pragma unroll
        for (int c = 0; c < 16; ++c) M = fmaxf(M, cpm[(size_t)r * 16 + c]);
        float S = 0.0f;
#pragma unroll
        for (int c = 0; c < 16; ++c) S += cps[(size_t)r * 16 + c] * __expf(cpm[(size_t)r * 16 + c] - M);
        local += (M + logf(S)) - tgt[r];
    }
    red[threadIdx.x] = local;
    __syncthreads();
    for (int o = 128; o; o >>= 1) {
        if (threadIdx.x < o) red[threadIdx.x] += red[threadIdx.x + o];
        __syncthreads();
    }
    if (threadIdx.x == 0) out[0] = red[0] * (128.0f / 4128.0f);
}

extern "C" void kernel_launch(void* const* d_in, const int* in_sizes, int n_in,
                              void* d_out, int out_size, void* d_ws, size_t ws_size,
                              hipStream_t stream) {
    const int*   padded = (const int*)d_in[0];
    const float* enc    = (const float*)d_in[1];
    const float* emb    = (const float*)d_in[2];
    const float* W_ih0  = (const float*)d_in[3];
    const float* b_ih0  = (const float*)d_in[4];
    const float* W_hh0  = (const float*)d_in[5];
    const float* b_hh0  = (const float*)d_in[6];
    const float* W_ih1  = (const float*)d_in[7];
    const float* b_ih1  = (const float*)d_in[8];
    const float* W_hh1  = (const float*)d_in[9];
    const float* b_hh1  = (const float*)d_in[10];
    const float* W1     = (const float*)d_in[11];
    const float* b1     = (const float*)d_in[12];
    const float* W2     = (const float*)d_in[13];
    const float* b2     = (const float*)d_in[14];
    float* ws  = (float*)d_ws;
    float* out = (float*)d_out;

    hipLaunchKernelGGL(k_init, dim3(321), dim3(256), 0, stream, ws);
    hipLaunchKernelGGL(k_pack0, dim3(8192), dim3(256), 0, stream, W_ih0, W_hh0, ws + OFF_WP0);
    hipLaunchKernelGGL(k_pack1, dim3(8192), dim3(256), 0, stream, W_ih1, W_hh1, ws + OFF_WP1);
    hipLaunchKernelGGL(k_xpre, dim3(129, 32), dim3(256), 0, stream,
                       padded, emb, W_ih0, b_ih0, b_hh0, ws + OFF_XPRE);
    {
        float* ws_a = ws;
        const float* enc_a = enc;
        const float* bia = b_ih1;
        const float* bib = b_hh1;
        void* args[] = {(void*)&ws_a, (void*)&enc_a, (void*)&bia, (void*)&bib};
        hipLaunchCooperativeKernel((void*)k_seq, dim3(256), dim3(256), args, 0, stream);
    }
    hipLaunchKernelGGL(k_mlp, dim3(129, 8), dim3(256), 0, stream,
                       ws + OFF_H1A, ws + OFF_ATTC, W1, b1, ws + OFF_HID);
    hipLaunchKernelGGL(k_ce, dim3(129, 16), dim3(256), 0, stream,
                       ws + OFF_HID, W2, b2, padded, ws + OFF_CPM, ws + OFF_CPS, ws + OFF_TGT);
    hipLaunchKernelGGL(k_final, dim3(1), dim3(256), 0, stream,
                       ws + OFF_CPM, ws + OFF_CPS, ws + OFF_TGT, out);
}

// Round 4
// 6186.618 us; speedup vs baseline: 1.9000x; 1.9000x over previous
//
#include <hip/hip_runtime.h>

typedef unsigned short us_t;
typedef unsigned int u32;

// Problem constants
constexpr int V = 4000, E = 512, H = 512, NB = 32, To = 128, Ti = 512;
constexpr int T_STEPS = 129;          // To + 1

// ws layout (float offsets)
constexpr size_t OFF_XPRE = 0;                                   // f [129][32][2048]
constexpr size_t OFF_WP0  = OFF_XPRE + (size_t)129*32*2048;      // us [256][1024][8]
constexpr size_t OFF_WP1  = OFF_WP0 + (size_t)256*1024*8/2;
constexpr size_t OFF_H0B  = OFF_WP1 + (size_t)256*1024*8/2;      // us [130][512][32]
constexpr size_t OFF_H1B  = OFF_H0B + (size_t)130*16384/2;
constexpr size_t OFF_ATB  = OFF_H1B + (size_t)130*16384/2;
constexpr size_t OFF_H1T  = OFF_ATB + (size_t)130*16384/2;       // us [130][32][520]
constexpr size_t OFF_HID  = OFF_H1T + (size_t)130*16640/2;       // f [4128][512]
constexpr size_t OFF_PM   = OFF_HID + (size_t)4128*512;          // f [256]
constexpr size_t OFF_PS   = OFF_PM + 256;
constexpr size_t OFF_PCTX = OFF_PS + 256;                        // f [256][512]
constexpr size_t OFF_CPM  = OFF_PCTX + (size_t)256*512;          // f [4128][16]
constexpr size_t OFF_CPS  = OFF_CPM + (size_t)4128*16;
constexpr size_t OFF_TGT  = OFF_CPS + (size_t)4128*16;           // f [4128]
constexpr size_t OFF_FLG  = OFF_TGT + 4128;                      // u32 [256]

__device__ __forceinline__ float sigmf(float x) { return 1.0f / (1.0f + __expf(-x)); }
__device__ __forceinline__ float bfl(u32 u) { return __uint_as_float(u << 16); }
__device__ __forceinline__ float bfh(u32 u) { return __uint_as_float(u & 0xffff0000u); }
__device__ __forceinline__ us_t f2b(float x) {
    u32 u = __float_as_uint(x);
    return (us_t)((u + 0x7fffu + ((u >> 16) & 1u)) >> 16);
}

// ---- grid sync primitives: per-block epoch flags, no acquire-invalidate ----
__device__ __forceinline__ void arrive(u32* flg, int b, int tid, u32 val, bool fence) {
    __syncthreads();   // compiler emits vmcnt wait: all block stores at least in L2
    if (tid == 0) {
        if (fence) __builtin_amdgcn_fence(__ATOMIC_RELEASE, "agent");  // wb dirty L2 -> L3
        __hip_atomic_store(flg + b, val, __ATOMIC_RELAXED, __HIP_MEMORY_SCOPE_AGENT);
    }
}
__device__ __forceinline__ void wait_all(u32* flg, u32 target, int tid) {
    if (tid < 64) {
        for (;;) {
            u32 a = __hip_atomic_load(flg + tid,       __ATOMIC_RELAXED, __HIP_MEMORY_SCOPE_AGENT);
            u32 c = __hip_atomic_load(flg + 64 + tid,  __ATOMIC_RELAXED, __HIP_MEMORY_SCOPE_AGENT);
            u32 d = __hip_atomic_load(flg + 128 + tid, __ATOMIC_RELAXED, __HIP_MEMORY_SCOPE_AGENT);
            u32 e = __hip_atomic_load(flg + 192 + tid, __ATOMIC_RELAXED, __HIP_MEMORY_SCOPE_AGENT);
            int ok = (a >= target) && (c >= target) && (d >= target) && (e >= target);
            if (__all(ok)) break;
            __builtin_amdgcn_s_sleep(1);
        }
    }
    __syncthreads();   // also orders subsequent plain loads after poll exit
}

// ---------------- init: zero state slab-0 + flags ----------------
__global__ __launch_bounds__(256) void k_init(float* ws) {
    int id = blockIdx.x * 256 + threadIdx.x;   // 0..24831
    if (id < 8192)        ws[OFF_H0B + id] = 0.0f;       // slab 0 (bf16 zeros)
    else if (id < 16384)  ws[OFF_H1B + (id - 8192)] = 0.0f;
    else if (id < 24576)  ws[OFF_ATB + (id - 16384)] = 0.0f;
    else                  ws[OFF_FLG + (id - 24576)] = 0.0f;
}

// ---------------- weight pre-pack (bf16): Wp[b][k][r], block b owns 8 g-rows ----------------
__global__ __launch_bounds__(256) void k_pack0(const float* __restrict__ W_ih0,
                                               const float* __restrict__ W_hh0,
                                               us_t* __restrict__ Wp) {
    int p = blockIdx.x * 256 + threadIdx.x;    // 0..2097151
    int r = p & 7, k = (p >> 3) & 1023, b = p >> 13;
    int gRow = ((r >> 1) & 3) * 512 + b * 2 + (r & 1);
    float v = (k < 512) ? W_ih0[(size_t)gRow * 1024 + 512 + k]
                        : W_hh0[(size_t)gRow * 512 + (k - 512)];
    Wp[p] = f2b(v);
}
__global__ __launch_bounds__(256) void k_pack1(const float* __restrict__ W_ih1,
                                               const float* __restrict__ W_hh1,
                                               us_t* __restrict__ Wp) {
    int p = blockIdx.x * 256 + threadIdx.x;
    int r = p & 7, k = (p >> 3) & 1023, b = p >> 13;
    int gRow = ((r >> 1) & 3) * 512 + b * 2 + (r & 1);
    float v = (k < 512) ? W_ih1[(size_t)gRow * 512 + k]
                        : W_hh1[(size_t)gRow * 512 + (k - 512)];
    Wp[p] = f2b(v);
}

// ---------------- X_pre GEMM (fp32, unchanged) ----------------
__global__ __launch_bounds__(256) void k_xpre(const int* __restrict__ padded,
                                              const float* __restrict__ embedding,
                                              const float* __restrict__ W_ih0,
                                              const float* __restrict__ b_ih0,
                                              const float* __restrict__ b_hh0,
                                              float* __restrict__ Xpre) {
    __shared__ __align__(16) float At[32 * 33];
    __shared__ __align__(16) float Bt[32 * 68];
    __shared__ int toks[32];
    const int t = blockIdx.x, j0 = blockIdx.y * 64, tid = threadIdx.x;
    if (tid < 32) toks[tid] = (t == 0) ? 1 : padded[tid * 128 + (t - 1)];
    __syncthreads();
    const int ty = tid >> 4, tx = tid & 15;
    float acc[8];
#pragma unroll
    for (int i = 0; i < 8; ++i) acc[i] = 0.0f;
    for (int k0 = 0; k0 < 512; k0 += 32) {
        __syncthreads();
        {
            int r = tid >> 3, kk4 = tid & 7;
            float4 v = *(const float4*)(embedding + (size_t)toks[r] * 512 + k0 + kk4 * 4);
            At[(kk4 * 4 + 0) * 33 + r] = v.x;
            At[(kk4 * 4 + 1) * 33 + r] = v.y;
            At[(kk4 * 4 + 2) * 33 + r] = v.z;
            At[(kk4 * 4 + 3) * 33 + r] = v.w;
#pragma unroll
            for (int i2 = 0; i2 < 2; ++i2) {
                int f = tid + 256 * i2;
                int j = f >> 3, kb = f & 7;
                float4 w = *(const float4*)(W_ih0 + (size_t)(j0 + j) * 1024 + k0 + kb * 4);
                Bt[(kb * 4 + 0) * 68 + j] = w.x;
                Bt[(kb * 4 + 1) * 68 + j] = w.y;
                Bt[(kb * 4 + 2) * 68 + j] = w.z;
                Bt[(kb * 4 + 3) * 68 + j] = w.w;
            }
        }
        __syncthreads();
#pragma unroll
        for (int kk = 0; kk < 32; ++kk) {
            float a0 = At[kk * 33 + ty], a1 = At[kk * 33 + ty + 16];
            float4 b4 = *(const float4*)&Bt[kk * 68 + tx * 4];
            acc[0] += a0 * b4.x; acc[1] += a0 * b4.y; acc[2] += a0 * b4.z; acc[3] += a0 * b4.w;
            acc[4] += a1 * b4.x; acc[5] += a1 * b4.y; acc[6] += a1 * b4.z; acc[7] += a1 * b4.w;
        }
    }
    int j = j0 + tx * 4;
    float4 bi = *(const float4*)(b_ih0 + j);
    float4 bh = *(const float4*)(b_hh0 + j);
    int r0 = t * 32;
    float4 o0 = {acc[0] + bi.x + bh.x, acc[1] + bi.y + bh.y, acc[2] + bi.z + bh.z, acc[3] + bi.w + bh.w};
    float4 o1 = {acc[4] + bi.x + bh.x, acc[5] + bi.y + bh.y, acc[6] + bi.z + bh.z, acc[7] + bi.w + bh.w};
    *(float4*)(Xpre + (size_t)(r0 + ty) * 2048 + j) = o0;
    *(float4*)(Xpre + (size_t)(r0 + ty + 16) * 2048 + j) = o1;
}

// ---------------- LSTM phase: bf16 weights in LDS, bf16 x staged coalesced ----------------
__device__ __forceinline__ void lstm_phase(
    const us_t* __restrict__ wp,         // LDS [1024][8] bf16
    const us_t* __restrict__ srcA,       // global slab [512][32] bf16
    const us_t* __restrict__ srcB,
    const float* __restrict__ xpre_row,  // or nullptr
    const float* __restrict__ bia, const float* __restrict__ bib,
    float& creg,
    us_t* __restrict__ hOut,             // slab [512][32] bf16
    us_t* __restrict__ hT,               // [32][520] bf16 slab or null
    int b, int tid, int q, int kq,
    us_t* xbuf, float* red, float* gv) {
    float acc[8][4];
#pragma unroll
    for (int r = 0; r < 8; ++r)
#pragma unroll
        for (int s = 0; s < 4; ++s) acc[r][s] = 0.0f;

    for (int s = 0; s < 2; ++s) {
        const uint2* g = (const uint2*)(s ? srcB : srcA);
        __syncthreads();
#pragma unroll
        for (int j = 0; j < 16; ++j) {
            int f = tid + j * 256;           // uint2 units (4 us) over 512x32 tile
            uint2 v = g[f];
            *(uint2*)(xbuf + (f >> 3) * 36 + (f & 7) * 4) = v;
        }
        __syncthreads();
#pragma unroll
        for (int i = 0; i < 16; ++i) {
            int lk = kq + 32 * i;
            uint2 xv = *(const uint2*)(xbuf + lk * 36 + q * 4);
            uint4 wv = *(const uint4*)(wp + (size_t)(s * 512 + lk) * 8);
            float xf[4] = {bfl(xv.x), bfh(xv.x), bfl(xv.y), bfh(xv.y)};
            float wf[8] = {bfl(wv.x), bfh(wv.x), bfl(wv.y), bfh(wv.y),
                           bfl(wv.z), bfh(wv.z), bfl(wv.w), bfh(wv.w)};
#pragma unroll
            for (int r = 0; r < 8; ++r)
#pragma unroll
                for (int s4 = 0; s4 < 4; ++s4) acc[r][s4] += wf[r] * xf[s4];
        }
    }
    // cross-kq reduction, 2 chunks of 4 rows
#pragma unroll
    for (int c = 0; c < 2; ++c) {
        __syncthreads();
#pragma unroll
        for (int r = 0; r < 4; ++r)
#pragma unroll
            for (int s = 0; s < 4; ++s)
                red[(q * 4 + s) * 132 + r * 33 + kq] = acc[c * 4 + r][s];
        __syncthreads();
        if (tid < 128) {
            int rr = tid >> 5, n = tid & 31;
            float gsum = 0.0f;
#pragma unroll
            for (int k2 = 0; k2 < 32; ++k2) gsum += red[n * 132 + rr * 33 + k2];
            gv[(c * 4 + rr) * 33 + n] = gsum;
        }
    }
    __syncthreads();
    if (tid < 64) {
        int jl = tid >> 5, nn = tid & 31;
        float gi = gv[(0 + jl) * 33 + nn];
        float gf = gv[(2 + jl) * 33 + nn];
        float gg = gv[(4 + jl) * 33 + nn];
        float go = gv[(6 + jl) * 33 + nn];
        int j = b * 2 + jl;
        if (xpre_row) {
            const float* xp = xpre_row + (size_t)nn * 2048;
            gi += xp[j]; gf += xp[512 + j]; gg += xp[1024 + j]; go += xp[1536 + j];
        } else {
            gi += bia[j] + bib[j];
            gf += bia[512 + j] + bib[512 + j];
            gg += bia[1024 + j] + bib[1024 + j];
            go += bia[1536 + j] + bib[1536 + j];
        }
        float cn = sigmf(gf) * creg + sigmf(gi) * tanhf(gg);
        float hn = sigmf(go) * tanhf(cn);
        creg = cn;
        // publish h: packed u32 sc1 stores (bypass L2 -> L3), pair along nn
        float hO = __shfl_xor(hn, 1);
        if ((nn & 1) == 0) {
            u32 pk = (u32)f2b(hn) | ((u32)f2b(hO) << 16);
            __hip_atomic_store((u32*)hOut + (j * 16 + (nn >> 1)), pk,
                               __ATOMIC_RELAXED, __HIP_MEMORY_SCOPE_AGENT);
        }
        if (hT) {
            float hJ = __shfl_xor(hn, 32);   // partner jl
            if (jl == 0) {
                u32 pk = (u32)f2b(hn) | ((u32)f2b(hJ) << 16);
                __hip_atomic_store((u32*)hT + (nn * 260 + b), pk,
                                   __ATOMIC_RELAXED, __HIP_MEMORY_SCOPE_AGENT);
            }
        }
    }
}

// ---------------- cooperative sequential kernel ----------------
__global__ __launch_bounds__(256, 1) void k_seq(float* ws,
                                                const float* __restrict__ enc,
                                                const float* __restrict__ b_ih1,
                                                const float* __restrict__ b_hh1) {
    __shared__ __align__(16) us_t lds_w[16384];      // 32 KB: both weight packs bf16
    __shared__ __align__(16) us_t lds_e[64 * 552];   // 69 KB: enc slice bf16, skewed
    __shared__ __align__(16) us_t lds_x[512 * 36];   // 36 KB: x staging (aliased as f32 scratch)
    __shared__ __align__(16) float gv[264];

    const int b = blockIdx.x, tid = threadIdx.x;
    const int q = tid >> 5, kq = tid & 31;
    float* red = (float*)lds_x;

    float* Xpre = ws + OFF_XPRE;
    us_t* h0b  = (us_t*)(ws + OFF_H0B);
    us_t* h1b  = (us_t*)(ws + OFF_H1B);
    us_t* atb  = (us_t*)(ws + OFF_ATB);
    us_t* h1T  = (us_t*)(ws + OFF_H1T);
    float* pm  = ws + OFF_PM;
    float* ps  = ws + OFF_PS;
    float* pctx = ws + OFF_PCTX;
    u32* flg = (u32*)(ws + OFF_FLG);

    float c0r = 0.0f, c1r = 0.0f;

    // ---- one-time LDS residency ----
    {
        const uint4* w0 = (const uint4*)((const us_t*)(ws + OFF_WP0) + (size_t)b * 8192);
        const uint4* w1 = (const uint4*)((const us_t*)(ws + OFF_WP1) + (size_t)b * 8192);
#pragma unroll
        for (int f = tid; f < 1024; f += 256) ((uint4*)lds_w)[f] = w0[f];
#pragma unroll
        for (int f = tid; f < 1024; f += 256) ((uint4*)(lds_w + 8192))[f] = w1[f];
        const int n = b >> 3, ts0 = (b & 7) * 64;
        const float4* encn = (const float4*)(enc + ((size_t)n * 512 + ts0) * 512);
#pragma unroll 4
        for (int j = 0; j < 32; ++j) {
            int f = tid + j * 256;
            int row = f >> 7, c4 = f & 127;
            float4 v = encn[(size_t)row * 128 + c4];
            ushort4 o;
            o.x = f2b(v.x); o.y = f2b(v.y); o.z = f2b(v.z); o.w = f2b(v.w);
            *(ushort4*)(lds_e + (size_t)row * 552 + (c4 >> 5) * 136 + (c4 & 31) * 4) = o;
        }
    }
    __syncthreads();

    for (int t = 0; t < T_STEPS; ++t) {
        const u32 e0 = 4u * t;
        wait_all(flg, e0, tid);          // attc[t], h0b[t], h1b[t] slabs published
        // ---- P1: LSTM0 ----
        lstm_phase(lds_w, atb + (size_t)t * 16384, h0b + (size_t)t * 16384,
                   Xpre + (size_t)t * 65536, nullptr, nullptr,
                   c0r, h0b + (size_t)(t + 1) * 16384, nullptr,
                   b, tid, q, kq, lds_x, red, gv);
        arrive(flg, b, tid, e0 + 1, true);
        wait_all(flg, e0 + 1, tid);
        // ---- P2: LSTM1 ----
        lstm_phase(lds_w + 8192, h0b + (size_t)(t + 1) * 16384, h1b + (size_t)t * 16384,
                   nullptr, b_ih1, b_hh1,
                   c1r, h1b + (size_t)(t + 1) * 16384, h1T + (size_t)(t + 1) * 16640,
                   b, tid, q, kq, lds_x, red, gv);
        arrive(flg, b, tid, e0 + 2, true);
        wait_all(flg, e0 + 2, tid);
        // ---- P3a: attention chunk (8 blocks/sample, 64 frames each) ----
        {
            const int n = b >> 3;
            float* h_l = red;          // 512 f
            float* scp = red + 512;    // 256 f
            float* p_l = red + 768;    // 64 f
            {
                u32 hv = *(const u32*)(h1T + (size_t)(t + 1) * 16640 + n * 520 + tid * 2);
                float2 h2 = {bfl(hv), bfh(hv)};
                *(float2*)(h_l + tid * 2) = h2;
            }
            __syncthreads();
            {
                int ti = tid >> 2, kp = tid & 3;
                const us_t* er = lds_e + (size_t)ti * 552 + kp * 136;
                const float* hr = h_l + kp * 128;
                float s = 0.0f;
#pragma unroll
                for (int k8 = 0; k8 < 16; ++k8) {
                    uint4 u = *(const uint4*)(er + k8 * 8);
                    const float* h8 = hr + k8 * 8;
                    s += bfl(u.x) * h8[0] + bfh(u.x) * h8[1]
                       + bfl(u.y) * h8[2] + bfh(u.y) * h8[3]
                       + bfl(u.z) * h8[4] + bfh(u.z) * h8[5]
                       + bfl(u.w) * h8[6] + bfh(u.w) * h8[7];
                }
                scp[kp * 64 + ti] = s;
            }
            __syncthreads();
            if (tid < 64) {
                float sc = scp[tid] + scp[64 + tid] + scp[128 + tid] + scp[192 + tid];
                float m = sc;
                for (int o = 32; o; o >>= 1) m = fmaxf(m, __shfl_xor(m, o));
                float e = __expf(sc - m);
                float z = e;
                for (int o = 32; o; o >>= 1) z += __shfl_xor(z, o);
                p_l[tid] = e;
                if (tid == 0) { pm[b] = m; ps[b] = z; }
            }
            __syncthreads();
            {
                int f0 = tid * 2;
                const us_t* eb = lds_e + (f0 >> 7) * 136 + (f0 & 127);
                float cv0 = 0.0f, cv1 = 0.0f;
#pragma unroll 8
                for (int ti = 0; ti < 64; ++ti) {
                    float w = p_l[ti];
                    u32 u = *(const u32*)(eb + (size_t)ti * 552);
                    cv0 += w * bfl(u); cv1 += w * bfh(u);
                }
                float2 o2 = {cv0, cv1};
                *(float2*)&pctx[(size_t)b * 512 + f0] = o2;
            }
        }
        arrive(flg, b, tid, e0 + 3, true);   // fence: pm/ps/pctx are plain stores
        // ---- P3b: combine -> attc(t+1), 32 blocks, bypass reads, packed u32 writes ----
        if (b < 32) {
            wait_all(flg, e0 + 3, tid);
            float* pmL = red;        // 256
            float* psL = red + 256;  // 256
            pmL[tid] = __hip_atomic_load(pm + tid, __ATOMIC_RELAXED, __HIP_MEMORY_SCOPE_AGENT);
            psL[tid] = __hip_atomic_load(ps + tid, __ATOMIC_RELAXED, __HIP_MEMORY_SCOPE_AGENT);
            __syncthreads();
            int np = tid >> 4, kk = tid & 15;
            int k = b * 16 + kk;
            u32 outw = 0;
#pragma unroll
            for (int hh = 0; hh < 2; ++hh) {
                int n = np * 2 + hh;
                float M = -1e30f;
#pragma unroll
                for (int c = 0; c < 8; ++c) M = fmaxf(M, pmL[n * 8 + c]);
                float Z = 0.0f, ctx = 0.0f;
#pragma unroll
                for (int c = 0; c < 8; ++c) {
                    float scl = __expf(pmL[n * 8 + c] - M);
                    Z += psL[n * 8 + c] * scl;
                    float pv = __hip_atomic_load(pctx + (size_t)(n * 8 + c) * 512 + k,
                                                 __ATOMIC_RELAXED, __HIP_MEMORY_SCOPE_AGENT);
                    ctx += pv * scl;
                }
                outw |= ((u32)f2b(ctx / Z)) << (16 * hh);
            }
            __hip_atomic_store((u32*)atb + ((size_t)(t + 1) * 8192 + k * 16 + np), outw,
                               __ATOMIC_RELAXED, __HIP_MEMORY_SCOPE_AGENT);
            arrive(flg, b, tid, e0 + 4, true);
        } else {
            arrive(flg, b, tid, e0 + 4, false);
        }
    }
}

// ---------------- MLP hidden GEMM (bf16 inputs): hidden = tanh([h1,attc] @ W1.T + b1) ----------------
__global__ __launch_bounds__(256) void k_mlp(const us_t* __restrict__ h1b,
                                             const us_t* __restrict__ atb,
                                             const float* __restrict__ W1,
                                             const float* __restrict__ b1,
                                             float* __restrict__ hidden) {
    __shared__ __align__(16) float At[32 * 33];
    __shared__ __align__(16) float Bt[32 * 68];
    const int t = blockIdx.x, j0 = blockIdx.y * 64, tid = threadIdx.x;
    const int ty = tid >> 4, tx = tid & 15;
    float acc[8];
#pragma unroll
    for (int i = 0; i < 8; ++i) acc[i] = 0.0f;
    for (int k0 = 0; k0 < 1024; k0 += 32) {
        const us_t* src = (k0 < 512) ? (h1b + (size_t)(t + 1) * 16384 + (size_t)k0 * 32)
                                     : (atb + (size_t)(t + 1) * 16384 + (size_t)(k0 - 512) * 32);
        __syncthreads();
        {
            int kk = tid >> 3, n4 = tid & 7;
            uint2 v = *(const uint2*)(src + (size_t)kk * 32 + n4 * 4);
            At[kk * 33 + n4 * 4 + 0] = bfl(v.x);
            At[kk * 33 + n4 * 4 + 1] = bfh(v.x);
            At[kk * 33 + n4 * 4 + 2] = bfl(v.y);
            At[kk * 33 + n4 * 4 + 3] = bfh(v.y);
#pragma unroll
            for (int i2 = 0; i2 < 2; ++i2) {
                int f = tid + 256 * i2;
                int j = f >> 3, kb = f & 7;
                float4 w = *(const float4*)(W1 + (size_t)(j0 + j) * 1024 + k0 + kb * 4);
                Bt[(kb * 4 + 0) * 68 + j] = w.x;
                Bt[(kb * 4 + 1) * 68 + j] = w.y;
                Bt[(kb * 4 + 2) * 68 + j] = w.z;
                Bt[(kb * 4 + 3) * 68 + j] = w.w;
            }
        }
        __syncthreads();
#pragma unroll
        for (int kk = 0; kk < 32; ++kk) {
            float a0 = At[kk * 33 + ty], a1 = At[kk * 33 + ty + 16];
            float4 b4 = *(const float4*)&Bt[kk * 68 + tx * 4];
            acc[0] += a0 * b4.x; acc[1] += a0 * b4.y; acc[2] += a0 * b4.z; acc[3] += a0 * b4.w;
            acc[4] += a1 * b4.x; acc[5] += a1 * b4.y; acc[6] += a1 * b4.z; acc[7] += a1 * b4.w;
        }
    }
    int j = j0 + tx * 4;
    float4 bv = *(const float4*)(b1 + j);
    int r0 = t * 32;
    float4 o0 = {tanhf(acc[0] + bv.x), tanhf(acc[1] + bv.y), tanhf(acc[2] + bv.z), tanhf(acc[3] + bv.w)};
    float4 o1 = {tanhf(acc[4] + bv.x), tanhf(acc[5] + bv.y), tanhf(acc[6] + bv.z), tanhf(acc[7] + bv.w)};
    *(float4*)(hidden + (size_t)(r0 + ty) * 512 + j) = o0;
    *(float4*)(hidden + (size_t)(r0 + ty + 16) * 512 + j) = o1;
}

// ---------------- fused logits + chunk logsumexp ----------------
__global__ __launch_bounds__(256) void k_ce(const float* __restrict__ hidden,
                                            const float* __restrict__ W2,
                                            const float* __restrict__ b2,
                                            const int* __restrict__ padded,
                                            float* __restrict__ cpm, float* __restrict__ cps,
                                            float* __restrict__ tgt) {
    __shared__ __align__(16) float lg[256 * 33];
    __shared__ float mred[8 * 32];
    __shared__ float Mf[32];
    __shared__ float sred[8 * 32];
    const int t = blockIdx.x, vc = blockIdx.y, tid = threadIdx.x;
    const int v = vc * 256 + tid;
    const float* hrow = hidden + (size_t)t * 32 * 512;
    if (v < V) {
        float acc[32];
#pragma unroll
        for (int n = 0; n < 32; ++n) acc[n] = 0.0f;
        const float* w = W2 + (size_t)v * 512;
        for (int k4 = 0; k4 < 128; ++k4) {
            float4 a = *(const float4*)(w + k4 * 4);
#pragma unroll
            for (int n = 0; n < 32; ++n) {
                float4 h = *(const float4*)(hrow + (size_t)n * 512 + k4 * 4);
                acc[n] += a.x * h.x + a.y * h.y + a.z * h.z + a.w * h.w;
            }
        }
        float bb = b2[v];
#pragma unroll
        for (int n = 0; n < 32; ++n) lg[tid * 33 + n] = acc[n] + bb;
    } else {
#pragma unroll
        for (int n = 0; n < 32; ++n) lg[tid * 33 + n] = -1e30f;
    }
    __syncthreads();
    {
        int n = tid & 31, c = tid >> 5;
        float m = -1e30f;
        for (int i = 0; i < 32; ++i) m = fmaxf(m, lg[(c * 32 + i) * 33 + n]);
        mred[c * 32 + n] = m;
    }
    __syncthreads();
    if (tid < 32) {
        float M = mred[tid];
#pragma unroll
        for (int c = 1; c < 8; ++c) M = fmaxf(M, mred[c * 32 + tid]);
        Mf[tid] = M;
    }
    __syncthreads();
    {
        int n = tid & 31, c = tid >> 5;
        float M = Mf[n], s = 0.0f;
        for (int i = 0; i < 32; ++i) s += __expf(lg[(c * 32 + i) * 33 + n] - M);
        sred[c * 32 + n] = s;
    }
    __syncthreads();
    if (tid < 32) {
        int n = tid;
        float S = 0.0f;
#pragma unroll
        for (int c = 0; c < 8; ++c) S += sred[c * 32 + n];
        int r = t * 32 + n;
        cpm[(size_t)r * 16 + vc] = Mf[n];
        cps[(size_t)r * 16 + vc] = S;
        int vstar = (t < 128) ? padded[n * 128 + t] : 2;
        int vl = vstar - vc * 256;
        if (vl >= 0 && vl < 256) tgt[r] = lg[vl * 33 + n];
    }
}

// ---------------- final combine + CE reduction ----------------
__global__ __launch_bounds__(256) void k_final(const float* __restrict__ cpm,
                                               const float* __restrict__ cps,
                                               const float* __restrict__ tgt,
                                               float* __restrict__ out) {
    __shared__ float red[256];
    float local = 0.0f;
    for (int r = threadIdx.x; r < 4128; r += 256) {
        float M = -1e30f;
#pragma unroll
        for (int c = 0; c < 16; ++c) M = fmaxf(M, cpm[(size_t)r * 16 + c]);
        float S = 0.0f;
#pragma unroll
        for (int c = 0; c < 16; ++c) S += cps[(size_t)r * 16 + c] * __expf(cpm[(size_t)r * 16 + c] - M);
        local += (M + logf(S)) - tgt[r];
    }
    red[threadIdx.x] = local;
    __syncthreads();
    for (int o = 128; o; o >>= 1) {
        if (threadIdx.x < o) red[threadIdx.x] += red[threadIdx.x + o];
        __syncthreads();
    }
    if (threadIdx.x == 0) out[0] = red[0] * (128.0f / 4128.0f);
}

extern "C" void kernel_launch(void* const* d_in, const int* in_sizes, int n_in,
                              void* d_out, int out_size, void* d_ws, size_t ws_size,
                              hipStream_t stream) {
    const int*   padded = (const int*)d_in[0];
    const float* enc    = (const float*)d_in[1];
    const float* emb    = (const float*)d_in[2];
    const float* W_ih0  = (const float*)d_in[3];
    const float* b_ih0  = (const float*)d_in[4];
    const float* W_hh0  = (const float*)d_in[5];
    const float* b_hh0  = (const float*)d_in[6];
    const float* W_ih1  = (const float*)d_in[7];
    const float* b_ih1  = (const float*)d_in[8];
    const float* W_hh1  = (const float*)d_in[9];
    const float* b_hh1  = (const float*)d_in[10];
    const float* W1     = (const float*)d_in[11];
    const float* b1     = (const float*)d_in[12];
    const float* W2     = (const float*)d_in[13];
    const float* b2     = (const float*)d_in[14];
    float* ws  = (float*)d_ws;
    float* out = (float*)d_out;

    hipLaunchKernelGGL(k_init, dim3(97), dim3(256), 0, stream, ws);
    hipLaunchKernelGGL(k_pack0, dim3(8192), dim3(256), 0, stream,
                       W_ih0, W_hh0, (us_t*)(ws + OFF_WP0));
    hipLaunchKernelGGL(k_pack1, dim3(8192), dim3(256), 0, stream,
                       W_ih1, W_hh1, (us_t*)(ws + OFF_WP1));
    hipLaunchKernelGGL(k_xpre, dim3(129, 32), dim3(256), 0, stream,
                       padded, emb, W_ih0, b_ih0, b_hh0, ws + OFF_XPRE);
    {
        float* ws_a = ws;
        const float* enc_a = enc;
        const float* bia = b_ih1;
        const float* bib = b_hh1;
        void* args[] = {(void*)&ws_a, (void*)&enc_a, (void*)&bia, (void*)&bib};
        hipLaunchCooperativeKernel((void*)k_seq, dim3(256), dim3(256), args, 0, stream);
    }
    hipLaunchKernelGGL(k_mlp, dim3(129, 8), dim3(256), 0, stream,
                       (const us_t*)(ws + OFF_H1B), (const us_t*)(ws + OFF_ATB), W1, b1, ws + OFF_HID);
    hipLaunchKernelGGL(k_ce, dim3(129, 16), dim3(256), 0, stream,
                       ws + OFF_HID, W2, b2, padded, ws + OFF_CPM, ws + OFF_CPS, ws + OFF_TGT);
    hipLaunchKernelGGL(k_final, dim3(1), dim3(256), 0, stream,
                       ws + OFF_CPM, ws + OFF_CPS, ws + OFF_TGT, out);
}

// Round 5
// 5037.233 us; speedup vs baseline: 2.3335x; 1.2282x over previous
//
#include <hip/hip_runtime.h>

typedef unsigned short us_t;
typedef unsigned int u32;
typedef unsigned long long u64;

// Problem constants
constexpr int V = 4000, E = 512, H = 512, NB = 32, To = 128, Ti = 512;
constexpr int T_STEPS = 129;          // To + 1

// ws layout (float offsets)
constexpr size_t OFF_XPRE = 0;                                   // f [129][2048][32] (transposed!)
constexpr size_t OFF_WP0  = OFF_XPRE + (size_t)129*32*2048;      // us [256][1024][8]
constexpr size_t OFF_WP1  = OFF_WP0 + (size_t)256*1024*8/2;
constexpr size_t OFF_H0B  = OFF_WP1 + (size_t)256*1024*8/2;      // us [130][512][32]
constexpr size_t OFF_H1B  = OFF_H0B + (size_t)130*16384/2;
constexpr size_t OFF_H1T  = OFF_H1B + (size_t)130*16384/2;       // us [130][32][520]
constexpr size_t OFF_ATB  = OFF_H1T + (size_t)130*16640/2;       // us [130][512][32] bf16 attc
constexpr size_t OFF_CTX  = OFF_ATB + (size_t)130*16384/2;       // f [130][32][512] atomic acc
constexpr size_t OFF_MZ   = OFF_CTX + (size_t)130*16384;         // u64 [130][256]
constexpr size_t OFF_ZF   = OFF_MZ + (size_t)130*256*2;          // f [130][32]
constexpr size_t OFF_HID  = OFF_ZF + 130*32;                     // f [4128][512]
constexpr size_t OFF_CPM  = OFF_HID + (size_t)4128*512;          // f [4128][16]
constexpr size_t OFF_CPS  = OFF_CPM + (size_t)4128*16;
constexpr size_t OFF_TGT  = OFF_CPS + (size_t)4128*16;           // f [4128]
constexpr size_t OFF_FLG  = OFF_TGT + 4128;                      // u32 [256*16] spread flags

__device__ __forceinline__ float sigmf(float x) { return 1.0f / (1.0f + __expf(-x)); }
__device__ __forceinline__ float bfl(u32 u) { return __uint_as_float(u << 16); }
__device__ __forceinline__ float bfh(u32 u) { return __uint_as_float(u & 0xffff0000u); }
__device__ __forceinline__ us_t f2b(float x) {
    u32 u = __float_as_uint(x);
    return (us_t)((u + 0x7fffu + ((u >> 16) & 1u)) >> 16);
}

// ---- grid sync: per-block epoch flag (1/cacheline), sticky parallel poll ----
__device__ __forceinline__ void arrive(u32* flg, int b, int tid, u32 val) {
    __syncthreads();
    if (tid == 0) {
        __builtin_amdgcn_fence(__ATOMIC_RELEASE, "agent");
        __hip_atomic_store(flg + b * 16, val, __ATOMIC_RELAXED, __HIP_MEMORY_SCOPE_AGENT);
    }
}
__device__ __forceinline__ void wait_all(u32* flg, u32 target, int tid) {
    if (tid < 64) {
        bool d0 = false, d1 = false, d2 = false, d3 = false;
        for (;;) {
            if (!d0) d0 = __hip_atomic_load(flg + (tid)       * 16, __ATOMIC_RELAXED, __HIP_MEMORY_SCOPE_AGENT) >= target;
            if (!d1) d1 = __hip_atomic_load(flg + (64 + tid)  * 16, __ATOMIC_RELAXED, __HIP_MEMORY_SCOPE_AGENT) >= target;
            if (!d2) d2 = __hip_atomic_load(flg + (128 + tid) * 16, __ATOMIC_RELAXED, __HIP_MEMORY_SCOPE_AGENT) >= target;
            if (!d3) d3 = __hip_atomic_load(flg + (192 + tid) * 16, __ATOMIC_RELAXED, __HIP_MEMORY_SCOPE_AGENT) >= target;
            if (__all(d0 && d1 && d2 && d3)) break;
            __builtin_amdgcn_s_sleep(2);
        }
    }
    __syncthreads();
}

// ---------------- init ----------------
__global__ __launch_bounds__(256) void k_init(float* ws) {
    int t0 = blockIdx.x * 256 + threadIdx.x;
    int nth = gridDim.x * 256;
    float4 z4 = {0.f, 0.f, 0.f, 0.f};
    float4* c4 = (float4*)(ws + OFF_CTX);
    for (int i = t0; i < 130 * 32 * 128; i += nth) c4[i] = z4;
    float4* m4 = (float4*)(ws + OFF_MZ);
    for (int i = t0; i < 130 * 128; i += nth) m4[i] = z4;
    float4* h04 = (float4*)(ws + OFF_H0B);
    float4* h14 = (float4*)(ws + OFF_H1B);
    for (int i = t0; i < 2048; i += nth) { h04[i] = z4; h14[i] = z4; }
    u32* fl = (u32*)(ws + OFF_FLG);
    for (int i = t0; i < 4096; i += nth) fl[i] = 0u;
    if (t0 < 32) ws[OFF_ZF + t0] = 1.0f;
}

// ---------------- weight pre-pack (bf16): Wp[b][k][r], block b owns 8 g-rows ----------------
__global__ __launch_bounds__(256) void k_pack0(const float* __restrict__ W_ih0,
                                               const float* __restrict__ W_hh0,
                                               us_t* __restrict__ Wp) {
    int p = blockIdx.x * 256 + threadIdx.x;
    int r = p & 7, k = (p >> 3) & 1023, b = p >> 13;
    int gRow = ((r >> 1) & 3) * 512 + b * 2 + (r & 1);
    float v = (k < 512) ? W_ih0[(size_t)gRow * 1024 + 512 + k]
                        : W_hh0[(size_t)gRow * 512 + (k - 512)];
    Wp[p] = f2b(v);
}
__global__ __launch_bounds__(256) void k_pack1(const float* __restrict__ W_ih1,
                                               const float* __restrict__ W_hh1,
                                               us_t* __restrict__ Wp) {
    int p = blockIdx.x * 256 + threadIdx.x;
    int r = p & 7, k = (p >> 3) & 1023, b = p >> 13;
    int gRow = ((r >> 1) & 3) * 512 + b * 2 + (r & 1);
    float v = (k < 512) ? W_ih1[(size_t)gRow * 512 + k]
                        : W_hh1[(size_t)gRow * 512 + (k - 512)];
    Wp[p] = f2b(v);
}

// ---------------- X_pre GEMM, output TRANSPOSED [t][g][n] ----------------
__global__ __launch_bounds__(256) void k_xpre(const int* __restrict__ padded,
                                              const float* __restrict__ embedding,
                                              const float* __restrict__ W_ih0,
                                              const float* __restrict__ b_ih0,
                                              const float* __restrict__ b_hh0,
                                              float* __restrict__ Xpre) {
    __shared__ __align__(16) float At[32 * 33];
    __shared__ __align__(16) float Bt[32 * 68];
    __shared__ int toks[32];
    const int t = blockIdx.x, j0 = blockIdx.y * 64, tid = threadIdx.x;
    if (tid < 32) toks[tid] = (t == 0) ? 1 : padded[tid * 128 + (t - 1)];
    __syncthreads();
    const int ty = tid >> 4, tx = tid & 15;
    float acc[8];
#pragma unroll
    for (int i = 0; i < 8; ++i) acc[i] = 0.0f;
    for (int k0 = 0; k0 < 512; k0 += 32) {
        __syncthreads();
        {
            int r = tid >> 3, kk4 = tid & 7;
            float4 v = *(const float4*)(embedding + (size_t)toks[r] * 512 + k0 + kk4 * 4);
            At[(kk4 * 4 + 0) * 33 + r] = v.x;
            At[(kk4 * 4 + 1) * 33 + r] = v.y;
            At[(kk4 * 4 + 2) * 33 + r] = v.z;
            At[(kk4 * 4 + 3) * 33 + r] = v.w;
#pragma unroll
            for (int i2 = 0; i2 < 2; ++i2) {
                int f = tid + 256 * i2;
                int j = f >> 3, kb = f & 7;
                float4 w = *(const float4*)(W_ih0 + (size_t)(j0 + j) * 1024 + k0 + kb * 4);
                Bt[(kb * 4 + 0) * 68 + j] = w.x;
                Bt[(kb * 4 + 1) * 68 + j] = w.y;
                Bt[(kb * 4 + 2) * 68 + j] = w.z;
                Bt[(kb * 4 + 3) * 68 + j] = w.w;
            }
        }
        __syncthreads();
#pragma unroll
        for (int kk = 0; kk < 32; ++kk) {
            float a0 = At[kk * 33 + ty], a1 = At[kk * 33 + ty + 16];
            float4 b4 = *(const float4*)&Bt[kk * 68 + tx * 4];
            acc[0] += a0 * b4.x; acc[1] += a0 * b4.y; acc[2] += a0 * b4.z; acc[3] += a0 * b4.w;
            acc[4] += a1 * b4.x; acc[5] += a1 * b4.y; acc[6] += a1 * b4.z; acc[7] += a1 * b4.w;
        }
    }
    int j = j0 + tx * 4;
    float bi[4] = {b_ih0[j], b_ih0[j + 1], b_ih0[j + 2], b_ih0[j + 3]};
    float bh[4] = {b_hh0[j], b_hh0[j + 1], b_hh0[j + 2], b_hh0[j + 3]};
    float* base = Xpre + (size_t)t * 65536;
#pragma unroll
    for (int c = 0; c < 4; ++c) {
        base[(size_t)(j + c) * 32 + ty]      = acc[c]     + bi[c] + bh[c];
        base[(size_t)(j + c) * 32 + ty + 16] = acc[4 + c] + bi[c] + bh[c];
    }
}

// ---------------- staging helpers (into xl [256 k][35] f32) ----------------
__device__ __forceinline__ void stage_bf16_sub(const us_t* __restrict__ src,  // [256][32] bf16
                                               float* __restrict__ xl, int tid) {
    const uint2* g = (const uint2*)src;
#pragma unroll
    for (int j = 0; j < 8; ++j) {
        int f = j * 256 + tid;                 // uint2 index: k = f>>3, n4 = f&7
        uint2 v = g[f];
        float* d = xl + (f >> 3) * 35 + (f & 7) * 4;
        d[0] = bfl(v.x); d[1] = bfh(v.x); d[2] = bfl(v.y); d[3] = bfh(v.y);
    }
}
__device__ __forceinline__ void stage_ctx_sub(const float* __restrict__ ctx,  // [32][512] f32
                                              int k0, const float* __restrict__ invZ,
                                              float* __restrict__ xl, int tid) {
    const float4* g = (const float4*)ctx;
#pragma unroll
    for (int j = 0; j < 8; ++j) {
        int f = j * 256 + tid;                 // n = f>>6, k4 = f&63
        int n = f >> 6, k4 = f & 63;
        float4 v = g[(size_t)n * 128 + (k0 >> 2) + k4];
        float s = invZ[n];
        float* d = xl + (k4 * 4) * 35 + n;
        d[0]   = v.x * s;
        d[35]  = v.y * s;
        d[70]  = v.z * s;
        d[105] = v.w * s;
    }
}
__device__ __forceinline__ void compute_sub(const us_t* __restrict__ wp,  // LDS [256][8] bf16
                                            const float* __restrict__ xl,
                                            int q, int kq, float acc[8][4]) {
#pragma unroll
    for (int i = 0; i < 8; ++i) {
        int lk = kq + 32 * i;
        const float* xr = xl + lk * 35 + q * 4;
        float x0 = xr[0], x1 = xr[1], x2 = xr[2], x3 = xr[3];
        uint4 wv = *(const uint4*)(wp + (size_t)lk * 8);
        float wf[8] = {bfl(wv.x), bfh(wv.x), bfl(wv.y), bfh(wv.y),
                       bfl(wv.z), bfh(wv.z), bfl(wv.w), bfh(wv.w)};
#pragma unroll
        for (int r = 0; r < 8; ++r) {
            acc[r][0] += wf[r] * x0; acc[r][1] += wf[r] * x1;
            acc[r][2] += wf[r] * x2; acc[r][3] += wf[r] * x3;
        }
    }
}

// ---------------- gate reduction + nonlinearity + publish ----------------
__device__ __forceinline__ void lstm_tail(float acc[8][4],
                                          const float* __restrict__ xpreT,  // [2048][32] or null
                                          const float* __restrict__ bia, const float* __restrict__ bib,
                                          float& creg,
                                          u32* __restrict__ hOut32,         // [512*16] packed pairs
                                          u32* __restrict__ hT32,           // [32][260] or null
                                          int b, int tid, int q, int kq,
                                          float* red, float* gv) {
#pragma unroll
    for (int c = 0; c < 2; ++c) {
        __syncthreads();
#pragma unroll
        for (int r = 0; r < 4; ++r)
#pragma unroll
            for (int s = 0; s < 4; ++s)
                red[r * 1056 + kq * 33 + q * 4 + s] = acc[c * 4 + r][s];
        __syncthreads();
        if (tid < 128) {
            int rr = tid >> 5, n = tid & 31;
            float g = 0.0f;
#pragma unroll
            for (int k2 = 0; k2 < 32; ++k2) g += red[rr * 1056 + k2 * 33 + n];
            gv[(c * 4 + rr) * 33 + n] = g;
        }
    }
    __syncthreads();
    if (tid < 64) {
        int jl = tid >> 5, nn = tid & 31;
        float gi = gv[(0 + jl) * 33 + nn];
        float gf = gv[(2 + jl) * 33 + nn];
        float gg = gv[(4 + jl) * 33 + nn];
        float go = gv[(6 + jl) * 33 + nn];
        int j = b * 2 + jl;
        if (xpreT) {
            gi += xpreT[(size_t)(0    + j) * 32 + nn];
            gf += xpreT[(size_t)(512  + j) * 32 + nn];
            gg += xpreT[(size_t)(1024 + j) * 32 + nn];
            go += xpreT[(size_t)(1536 + j) * 32 + nn];
        } else {
            gi += bia[j] + bib[j];
            gf += bia[512 + j] + bib[512 + j];
            gg += bia[1024 + j] + bib[1024 + j];
            go += bia[1536 + j] + bib[1536 + j];
        }
        float cn = sigmf(gf) * creg + sigmf(gi) * tanhf(gg);
        float hn = sigmf(go) * tanhf(cn);
        creg = cn;
        float hO = __shfl_xor(hn, 1);
        if ((nn & 1) == 0) {
            u32 pk = (u32)f2b(hn) | ((u32)f2b(hO) << 16);
            __hip_atomic_store(hOut32 + (j * 16 + (nn >> 1)), pk,
                               __ATOMIC_RELAXED, __HIP_MEMORY_SCOPE_AGENT);
        }
        if (hT32) {
            float hJ = __shfl_xor(hn, 32);
            if (jl == 0) {
                u32 pk = (u32)f2b(hn) | ((u32)f2b(hJ) << 16);
                __hip_atomic_store(hT32 + (nn * 260 + b), pk,
                                   __ATOMIC_RELAXED, __HIP_MEMORY_SCOPE_AGENT);
            }
        }
    }
}

// ---------------- cooperative sequential kernel ----------------
__global__ __launch_bounds__(256, 1) void k_seq(float* ws,
                                                const float* __restrict__ enc,
                                                const float* __restrict__ b_ih1,
                                                const float* __restrict__ b_hh1) {
    __shared__ __align__(16) us_t lds_w[16384];      // 32 KB both packs bf16
    __shared__ __align__(16) us_t lds_e[64 * 552];   // 69 KB enc slice bf16, skewed
    __shared__ __align__(16) float xl[256 * 35];     // 35.8 KB x tile / scratch
    __shared__ __align__(16) float gv[264];
    __shared__ float invZ[32];

    const int b = blockIdx.x, tid = threadIdx.x;
    const int q = tid >> 5, kq = tid & 31;
    float* red = xl;

    float* Xpre = ws + OFF_XPRE;
    us_t* h0b = (us_t*)(ws + OFF_H0B);
    us_t* h1b = (us_t*)(ws + OFF_H1B);
    u32*  h1T32 = (u32*)(ws + OFF_H1T);
    u32*  atb32 = (u32*)(ws + OFF_ATB);
    float* ctx = ws + OFF_CTX;
    u64*  mz  = (u64*)(ws + OFF_MZ);
    float* Zf = ws + OFF_ZF;
    u32* flg = (u32*)(ws + OFF_FLG);

    float c0r = 0.0f, c1r = 0.0f;

    // ---- one-time LDS residency ----
    {
        const uint4* w0 = (const uint4*)((const us_t*)(ws + OFF_WP0) + (size_t)b * 8192);
        const uint4* w1 = (const uint4*)((const us_t*)(ws + OFF_WP1) + (size_t)b * 8192);
        for (int f = tid; f < 1024; f += 256) ((uint4*)lds_w)[f] = w0[f];
        for (int f = tid; f < 1024; f += 256) ((uint4*)(lds_w + 8192))[f] = w1[f];
        const int n = b >> 3, ts0 = (b & 7) * 64;
        const float4* encn = (const float4*)(enc + ((size_t)n * 512 + ts0) * 512);
#pragma unroll 4
        for (int j = 0; j < 32; ++j) {
            int f = tid + j * 256;
            int row = f >> 7, c4 = f & 127;
            float4 v = encn[(size_t)row * 128 + c4];
            ushort4 o;
            o.x = f2b(v.x); o.y = f2b(v.y); o.z = f2b(v.z); o.w = f2b(v.w);
            *(ushort4*)(lds_e + (size_t)row * 552 + (c4 >> 5) * 136 + (c4 & 31) * 4) = o;
        }
    }
    __syncthreads();

    for (int t = 0; t < T_STEPS; ++t) {
        const u32 base = 3u * t;
        // ============ P1: LSTM0, x = [attc(t) K0..511 | h0(t) K512..1023] ============
        float acc[8][4];
#pragma unroll
        for (int r = 0; r < 8; ++r)
#pragma unroll
            for (int s = 0; s < 4; ++s) acc[r][s] = 0.0f;
        // early: h0(t) half (wp sub 2,3) — no barrier dependency
        {
            const us_t* h0s = h0b + (size_t)t * 16384;
#pragma unroll
            for (int s = 0; s < 2; ++s) {
                stage_bf16_sub(h0s + s * 8192, xl, tid);
                __syncthreads();
                compute_sub(lds_w + (2 + s) * 2048, xl, q, kq, acc);
                __syncthreads();
            }
        }
        wait_all(flg, base, tid);                  // attc(t) acc + Zf(t) ready
        if (tid < 32) invZ[tid] = 1.0f / Zf[(size_t)t * 32 + tid];
        __syncthreads();
        {
            const float* ctxs = ctx + (size_t)t * 16384;
#pragma unroll
            for (int s = 0; s < 2; ++s) {
                stage_ctx_sub(ctxs, s * 256, invZ, xl, tid);
                __syncthreads();
                // write back bf16 attc rows owned by this block (for k_mlp)
                if (((2 * b) >> 8) == s && tid < 32) {
                    int r = 2 * b + (tid >> 4);
                    int rl = r & 255;
                    int n2 = (tid & 15) * 2;
                    u32 pk = (u32)f2b(xl[rl * 35 + n2]) | ((u32)f2b(xl[rl * 35 + n2 + 1]) << 16);
                    __hip_atomic_store(atb32 + ((size_t)t * 8192 + r * 16 + (tid & 15)), pk,
                                       __ATOMIC_RELAXED, __HIP_MEMORY_SCOPE_AGENT);
                }
                compute_sub(lds_w + s * 2048, xl, q, kq, acc);
                __syncthreads();
            }
        }
        lstm_tail(acc, Xpre + (size_t)t * 65536, nullptr, nullptr, c0r,
                  (u32*)(h0b + (size_t)(t + 1) * 16384), nullptr, b, tid, q, kq, red, gv);
        arrive(flg, b, tid, base + 1);
        // ============ P2: LSTM1, x = [h0(t+1) K0..511 | h1(t) K512..1023] ============
#pragma unroll
        for (int r = 0; r < 8; ++r)
#pragma unroll
            for (int s = 0; s < 4; ++s) acc[r][s] = 0.0f;
        {
            const us_t* h1s = h1b + (size_t)t * 16384;
#pragma unroll
            for (int s = 0; s < 2; ++s) {
                stage_bf16_sub(h1s + s * 8192, xl, tid);
                __syncthreads();
                compute_sub(lds_w + 8192 + (2 + s) * 2048, xl, q, kq, acc);
                __syncthreads();
            }
        }
        wait_all(flg, base + 1, tid);
        {
            const us_t* h0s = h0b + (size_t)(t + 1) * 16384;
#pragma unroll
            for (int s = 0; s < 2; ++s) {
                stage_bf16_sub(h0s + s * 8192, xl, tid);
                __syncthreads();
                compute_sub(lds_w + 8192 + s * 2048, xl, q, kq, acc);
                __syncthreads();
            }
        }
        lstm_tail(acc, nullptr, b_ih1, b_hh1, c1r,
                  (u32*)(h1b + (size_t)(t + 1) * 16384), h1T32 + (size_t)(t + 1) * 8320,
                  b, tid, q, kq, red, gv);
        arrive(flg, b, tid, base + 2);
        // ============ ATTN: single-pass, 8 blocks/sample, mini-sync + atomic ctx ============
        wait_all(flg, base + 2, tid);
        {
            const int n = b >> 3, c = b & 7;
            float* h_l = red;          // 512
            float* scp = red + 512;    // 256
            float* p_l = red + 768;    // 64
            {
                u32 hv = h1T32[(size_t)(t + 1) * 8320 + n * 260 + tid];
                float2 h2 = {bfl(hv), bfh(hv)};
                *(float2*)(h_l + tid * 2) = h2;
            }
            __syncthreads();
            {
                int ti = tid >> 2, kp = tid & 3;
                const us_t* er = lds_e + (size_t)ti * 552 + kp * 136;
                const float* hr = h_l + kp * 128;
                float s = 0.0f;
#pragma unroll
                for (int k8 = 0; k8 < 16; ++k8) {
                    uint4 u = *(const uint4*)(er + k8 * 8);
                    const float* h8 = hr + k8 * 8;
                    s += bfl(u.x) * h8[0] + bfh(u.x) * h8[1]
                       + bfl(u.y) * h8[2] + bfh(u.y) * h8[3]
                       + bfl(u.z) * h8[4] + bfh(u.z) * h8[5]
                       + bfl(u.w) * h8[6] + bfh(u.w) * h8[7];
                }
                scp[kp * 64 + ti] = s;
            }
            __syncthreads();
            if (tid < 64) {
                float sc = scp[tid] + scp[64 + tid] + scp[128 + tid] + scp[192 + tid];
                float m = sc;
                for (int o = 32; o; o >>= 1) m = fmaxf(m, __shfl_xor(m, o));
                float e = __expf(sc - m);
                float z = e;
                for (int o = 32; o; o >>= 1) z += __shfl_xor(z, o);
                p_l[tid] = e;
                if (tid == 0) {
                    red[840] = m;      // own chunk max
                    u64 pk = ((u64)__float_as_uint(m) << 32) | (u64)__float_as_uint(z);
                    __hip_atomic_store(mz + ((size_t)(t + 1) * 256 + n * 8 + c), pk,
                                       __ATOMIC_RELAXED, __HIP_MEMORY_SCOPE_AGENT);
                }
            }
            // mini-sync among the 8 chunk blocks of this sample
            if (tid < 8) {
                u64 v;
                for (;;) {
                    v = __hip_atomic_load(mz + ((size_t)(t + 1) * 256 + n * 8 + tid),
                                          __ATOMIC_RELAXED, __HIP_MEMORY_SCOPE_AGENT);
                    if ((u32)v != 0u) break;
                    __builtin_amdgcn_s_sleep(1);
                }
                float mi = __uint_as_float((u32)(v >> 32));
                float zi = __uint_as_float((u32)v);
#pragma unroll
                for (int o = 1; o < 8; o <<= 1) {
                    float mo = __shfl_xor(mi, o);
                    float zo = __shfl_xor(zi, o);
                    float Mn = fmaxf(mi, mo);
                    zi = zi * __expf(mi - Mn) + zo * __expf(mo - Mn);
                    mi = Mn;
                }
                if (tid == 0) {
                    red[841] = __expf(red[840] - mi);   // scl for this chunk
                    if (c == 0)
                        __hip_atomic_store((u32*)(Zf + (size_t)(t + 1) * 32 + n), __float_as_uint(zi),
                                           __ATOMIC_RELAXED, __HIP_MEMORY_SCOPE_AGENT);
                }
            }
            __syncthreads();
            float scl = red[841];
            {
                int f0 = tid * 2;
                const us_t* eb = lds_e + (f0 >> 7) * 136 + (f0 & 127);
                float cv0 = 0.0f, cv1 = 0.0f;
#pragma unroll 8
                for (int ti = 0; ti < 64; ++ti) {
                    float w = p_l[ti];
                    u32 u = *(const u32*)(eb + (size_t)ti * 552);
                    cv0 += w * bfl(u); cv1 += w * bfh(u);
                }
                float* dst = ctx + (size_t)(t + 1) * 16384 + (size_t)n * 512 + f0;
                __hip_atomic_fetch_add(dst,     cv0 * scl, __ATOMIC_RELAXED, __HIP_MEMORY_SCOPE_AGENT);
                __hip_atomic_fetch_add(dst + 1, cv1 * scl, __ATOMIC_RELAXED, __HIP_MEMORY_SCOPE_AGENT);
            }
        }
        arrive(flg, b, tid, base + 3);
    }
    // tail: materialize bf16 attc(129) for k_mlp
    wait_all(flg, 3u * T_STEPS, tid);
    if (b < 32) {
        int r = b * 16 + (tid >> 4);
        int n2 = (tid & 15) * 2;
        float z0 = Zf[(size_t)129 * 32 + n2], z1 = Zf[(size_t)129 * 32 + n2 + 1];
        float v0 = ctx[(size_t)129 * 16384 + (size_t)n2 * 512 + r] / z0;
        float v1 = ctx[(size_t)129 * 16384 + (size_t)(n2 + 1) * 512 + r] / z1;
        u32 pk = (u32)f2b(v0) | ((u32)f2b(v1) << 16);
        __hip_atomic_store(atb32 + ((size_t)129 * 8192 + r * 16 + (tid & 15)), pk,
                           __ATOMIC_RELAXED, __HIP_MEMORY_SCOPE_AGENT);
    }
}

// ---------------- MLP hidden GEMM (bf16 inputs) ----------------
__global__ __launch_bounds__(256) void k_mlp(const us_t* __restrict__ h1b,
                                             const us_t* __restrict__ atb,
                                             const float* __restrict__ W1,
                                             const float* __restrict__ b1,
                                             float* __restrict__ hidden) {
    __shared__ __align__(16) float At[32 * 33];
    __shared__ __align__(16) float Bt[32 * 68];
    const int t = blockIdx.x, j0 = blockIdx.y * 64, tid = threadIdx.x;
    const int ty = tid >> 4, tx = tid & 15;
    float acc[8];
#pragma unroll
    for (int i = 0; i < 8; ++i) acc[i] = 0.0f;
    for (int k0 = 0; k0 < 1024; k0 += 32) {
        const us_t* src = (k0 < 512) ? (h1b + (size_t)(t + 1) * 16384 + (size_t)k0 * 32)
                                     : (atb + (size_t)(t + 1) * 16384 + (size_t)(k0 - 512) * 32);
        __syncthreads();
        {
            int kk = tid >> 3, n4 = tid & 7;
            uint2 v = *(const uint2*)(src + (size_t)kk * 32 + n4 * 4);
            At[kk * 33 + n4 * 4 + 0] = bfl(v.x);
            At[kk * 33 + n4 * 4 + 1] = bfh(v.x);
            At[kk * 33 + n4 * 4 + 2] = bfl(v.y);
            At[kk * 33 + n4 * 4 + 3] = bfh(v.y);
#pragma unroll
            for (int i2 = 0; i2 < 2; ++i2) {
                int f = tid + 256 * i2;
                int j = f >> 3, kb = f & 7;
                float4 w = *(const float4*)(W1 + (size_t)(j0 + j) * 1024 + k0 + kb * 4);
                Bt[(kb * 4 + 0) * 68 + j] = w.x;
                Bt[(kb * 4 + 1) * 68 + j] = w.y;
                Bt[(kb * 4 + 2) * 68 + j] = w.z;
                Bt[(kb * 4 + 3) * 68 + j] = w.w;
            }
        }
        __syncthreads();
#pragma unroll
        for (int kk = 0; kk < 32; ++kk) {
            float a0 = At[kk * 33 + ty], a1 = At[kk * 33 + ty + 16];
            float4 b4 = *(const float4*)&Bt[kk * 68 + tx * 4];
            acc[0] += a0 * b4.x; acc[1] += a0 * b4.y; acc[2] += a0 * b4.z; acc[3] += a0 * b4.w;
            acc[4] += a1 * b4.x; acc[5] += a1 * b4.y; acc[6] += a1 * b4.z; acc[7] += a1 * b4.w;
        }
    }
    int j = j0 + tx * 4;
    float4 bv = *(const float4*)(b1 + j);
    int r0 = t * 32;
    float4 o0 = {tanhf(acc[0] + bv.x), tanhf(acc[1] + bv.y), tanhf(acc[2] + bv.z), tanhf(acc[3] + bv.w)};
    float4 o1 = {tanhf(acc[4] + bv.x), tanhf(acc[5] + bv.y), tanhf(acc[6] + bv.z), tanhf(acc[7] + bv.w)};
    *(float4*)(hidden + (size_t)(r0 + ty) * 512 + j) = o0;
    *(float4*)(hidden + (size_t)(r0 + ty + 16) * 512 + j) = o1;
}

// ---------------- fused logits + chunk logsumexp ----------------
__global__ __launch_bounds__(256) void k_ce(const float* __restrict__ hidden,
                                            const float* __restrict__ W2,
                                            const float* __restrict__ b2,
                                            const int* __restrict__ padded,
                                            float* __restrict__ cpm, float* __restrict__ cps,
                                            float* __restrict__ tgt) {
    __shared__ __align__(16) float lg[256 * 33];
    __shared__ float mred[8 * 32];
    __shared__ float Mf[32];
    __shared__ float sred[8 * 32];
    const int t = blockIdx.x, vc = blockIdx.y, tid = threadIdx.x;
    const int v = vc * 256 + tid;
    const float* hrow = hidden + (size_t)t * 32 * 512;
    if (v < V) {
        float acc[32];
#pragma unroll
        for (int n = 0; n < 32; ++n) acc[n] = 0.0f;
        const float* w = W2 + (size_t)v * 512;
        for (int k4 = 0; k4 < 128; ++k4) {
            float4 a = *(const float4*)(w + k4 * 4);
#pragma unroll
            for (int n = 0; n < 32; ++n) {
                float4 h = *(const float4*)(hrow + (size_t)n * 512 + k4 * 4);
                acc[n] += a.x * h.x + a.y * h.y + a.z * h.z + a.w * h.w;
            }
        }
        float bb = b2[v];
#pragma unroll
        for (int n = 0; n < 32; ++n) lg[tid * 33 + n] = acc[n] + bb;
    } else {
#pragma unroll
        for (int n = 0; n < 32; ++n) lg[tid * 33 + n] = -1e30f;
    }
    __syncthreads();
    {
        int n = tid & 31, c = tid >> 5;
        float m = -1e30f;
        for (int i = 0; i < 32; ++i) m = fmaxf(m, lg[(c * 32 + i) * 33 + n]);
        mred[c * 32 + n] = m;
    }
    __syncthreads();
    if (tid < 32) {
        float M = mred[tid];
#pragma unroll
        for (int c = 1; c < 8; ++c) M = fmaxf(M, mred[c * 32 + tid]);
        Mf[tid] = M;
    }
    __syncthreads();
    {
        int n = tid & 31, c = tid >> 5;
        float M = Mf[n], s = 0.0f;
        for (int i = 0; i < 32; ++i) s += __expf(lg[(c * 32 + i) * 33 + n] - M);
        sred[c * 32 + n] = s;
    }
    __syncthreads();
    if (tid < 32) {
        int n = tid;
        float S = 0.0f;
#pragma unroll
        for (int c = 0; c < 8; ++c) S += sred[c * 32 + n];
        int r = t * 32 + n;
        cpm[(size_t)r * 16 + vc] = Mf[n];
        cps[(size_t)r * 16 + vc] = S;
        int vstar = (t < 128) ? padded[n * 128 + t] : 2;
        int vl = vstar - vc * 256;
        if (vl >= 0 && vl < 256) tgt[r] = lg[vl * 33 + n];
    }
}

// ---------------- final combine + CE reduction ----------------
__global__ __launch_bounds__(256) void k_final(const float* __restrict__ cpm,
                                               const float* __restrict__ cps,
                                               const float* __restrict__ tgt,
                                               float* __restrict__ out) {
    __shared__ float red[256];
    float local = 0.0f;
    for (int r = threadIdx.x; r < 4128; r += 256) {
        float M = -1e30f;
#pragma unroll
        for (int c = 0; c < 16; ++c) M = fmaxf(M, cpm[(size_t)r * 16 + c]);
        float S = 0.0f;
#pragma unroll
        for (int c = 0; c < 16; ++c) S += cps[(size_t)r * 16 + c] * __expf(cpm[(size_t)r * 16 + c] - M);
        local += (M + logf(S)) - tgt[r];
    }
    red[threadIdx.x] = local;
    __syncthreads();
    for (int o = 128; o; o >>= 1) {
        if (threadIdx.x < o) red[threadIdx.x] += red[threadIdx.x + o];
        __syncthreads();
    }
    if (threadIdx.x == 0) out[0] = red[0] * (128.0f / 4128.0f);
}

extern "C" void kernel_launch(void* const* d_in, const int* in_sizes, int n_in,
                              void* d_out, int out_size, void* d_ws, size_t ws_size,
                              hipStream_t stream) {
    const int*   padded = (const int*)d_in[0];
    const float* enc    = (const float*)d_in[1];
    const float* emb    = (const float*)d_in[2];
    const float* W_ih0  = (const float*)d_in[3];
    const float* b_ih0  = (const float*)d_in[4];
    const float* W_hh0  = (const float*)d_in[5];
    const float* b_hh0  = (const float*)d_in[6];
    const float* W_ih1  = (const float*)d_in[7];
    const float* b_ih1  = (const float*)d_in[8];
    const float* W_hh1  = (const float*)d_in[9];
    const float* b_hh1  = (const float*)d_in[10];
    const float* W1     = (const float*)d_in[11];
    const float* b1     = (const float*)d_in[12];
    const float* W2     = (const float*)d_in[13];
    const float* b2     = (const float*)d_in[14];
    float* ws  = (float*)d_ws;
    float* out = (float*)d_out;

    hipLaunchKernelGGL(k_init, dim3(640), dim3(256), 0, stream, ws);
    hipLaunchKernelGGL(k_pack0, dim3(8192), dim3(256), 0, stream,
                       W_ih0, W_hh0, (us_t*)(ws + OFF_WP0));
    hipLaunchKernelGGL(k_pack1, dim3(8192), dim3(256), 0, stream,
                       W_ih1, W_hh1, (us_t*)(ws + OFF_WP1));
    hipLaunchKernelGGL(k_xpre, dim3(129, 32), dim3(256), 0, stream,
                       padded, emb, W_ih0, b_ih0, b_hh0, ws + OFF_XPRE);
    {
        float* ws_a = ws;
        const float* enc_a = enc;
        const float* bia = b_ih1;
        const float* bib = b_hh1;
        void* args[] = {(void*)&ws_a, (void*)&enc_a, (void*)&bia, (void*)&bib};
        hipLaunchCooperativeKernel((void*)k_seq, dim3(256), dim3(256), args, 0, stream);
    }
    hipLaunchKernelGGL(k_mlp, dim3(129, 8), dim3(256), 0, stream,
                       (const us_t*)(ws + OFF_H1B), (const us_t*)(ws + OFF_ATB), W1, b1, ws + OFF_HID);
    hipLaunchKernelGGL(k_ce, dim3(129, 16), dim3(256), 0, stream,
                       ws + OFF_HID, W2, b2, padded, ws + OFF_CPM, ws + OFF_CPS, ws + OFF_TGT);
    hipLaunchKernelGGL(k_final, dim3(1), dim3(256), 0, stream,
                       ws + OFF_CPM, ws + OFF_CPS, ws + OFF_TGT, out);
}

// Round 6
// 3708.913 us; speedup vs baseline: 3.1693x; 1.3581x over previous
//
#include <hip/hip_runtime.h>

typedef unsigned short us_t;
typedef unsigned int u32;
typedef unsigned long long u64;
typedef __attribute__((ext_vector_type(8))) short bf16x8;
typedef __attribute__((ext_vector_type(4))) float f32x4;

// Problem constants
constexpr int V = 4000, E = 512, H = 512, NB = 32, To = 128, Ti = 512;
constexpr int T_STEPS = 129;          // To + 1

// ws layout (float offsets)
constexpr size_t OFF_XPRE = 0;                                   // f [129][2048][32] (transposed)
constexpr size_t OFF_WP0  = OFF_XPRE + (size_t)129*32*2048;      // us [256][1024][8]
constexpr size_t OFF_WP1  = OFF_WP0 + (size_t)256*1024*8/2;
constexpr size_t OFF_H0B  = OFF_WP1 + (size_t)256*1024*8/2;      // us [130][512][32]
constexpr size_t OFF_H1B  = OFF_H0B + (size_t)130*16384/2;
constexpr size_t OFF_H1T  = OFF_H1B + (size_t)130*16384/2;       // us [130][32][520]
constexpr size_t OFF_ATB  = OFF_H1T + (size_t)130*16640/2;       // us [130][512][32] bf16 attc
constexpr size_t OFF_CTX  = OFF_ATB + (size_t)130*16384/2;       // f [130][32][512] atomic acc (normalized)
constexpr size_t OFF_MZ   = OFF_CTX + (size_t)130*16384;         // u64 [130][256]
constexpr size_t OFF_HID  = OFF_MZ + (size_t)130*256*2;          // us [4128][512] bf16 hidden
constexpr size_t OFF_W2P  = OFF_HID + (size_t)4128*512;          // us [64][4096][8] packed W2
constexpr size_t OFF_CPM  = OFF_W2P + (size_t)64*4096*8/2;       // f [4128][16]
constexpr size_t OFF_CPS  = OFF_CPM + (size_t)4128*16;
constexpr size_t OFF_TGT  = OFF_CPS + (size_t)4128*16;           // f [4128]
constexpr size_t OFF_FLG  = OFF_TGT + 4128;                      // u32 [256] dense flags

__device__ __forceinline__ float sigmf(float x) { return 1.0f / (1.0f + __expf(-x)); }
__device__ __forceinline__ float bfl(u32 u) { return __uint_as_float(u << 16); }
__device__ __forceinline__ float bfh(u32 u) { return __uint_as_float(u & 0xffff0000u); }
__device__ __forceinline__ us_t f2b(float x) {
    u32 u = __float_as_uint(x);
    return (us_t)((u + 0x7fffu + ((u >> 16) & 1u)) >> 16);
}

// ---- grid sync: dense per-block epoch flags; all publishes are sc1 atomics so
// __syncthreads' vmcnt(0) drain is a sufficient release -> NO cache fence needed.
__device__ __forceinline__ void arrive(u32* flg, int b, int tid, u32 val) {
    __syncthreads();
    if (tid == 0)
        __hip_atomic_store(flg + b, val, __ATOMIC_RELAXED, __HIP_MEMORY_SCOPE_AGENT);
}
__device__ __forceinline__ void wait_all(u32* flg, u32 target, int tid) {
    if (tid < 128) {
        const u64* f8 = (const u64*)flg;
        bool done = false;
        for (;;) {
            if (!done) {
                u64 v = __hip_atomic_load(f8 + tid, __ATOMIC_RELAXED, __HIP_MEMORY_SCOPE_AGENT);
                done = ((u32)v >= target) && ((u32)(v >> 32) >= target);
            }
            if (__all((int)done)) break;
            __builtin_amdgcn_s_sleep(2);
        }
    }
    __syncthreads();
}

// ---------------- init ----------------
__global__ __launch_bounds__(256) void k_init(float* ws) {
    int t0 = blockIdx.x * 256 + threadIdx.x;
    int nth = gridDim.x * 256;
    float4 z4 = {0.f, 0.f, 0.f, 0.f};
    float4* c4 = (float4*)(ws + OFF_CTX);
    for (int i = t0; i < 130 * 32 * 128; i += nth) c4[i] = z4;
    float4* m4 = (float4*)(ws + OFF_MZ);
    for (int i = t0; i < 130 * 128; i += nth) m4[i] = z4;
    float4* h04 = (float4*)(ws + OFF_H0B);
    float4* h14 = (float4*)(ws + OFF_H1B);
    for (int i = t0; i < 2048; i += nth) { h04[i] = z4; h14[i] = z4; }
    u32* fl = (u32*)(ws + OFF_FLG);
    if (t0 < 256) fl[t0] = 0u;
}

// ---------------- weight pre-pack (bf16): Wp[b][k][r], block b owns 8 g-rows ----------------
__global__ __launch_bounds__(256) void k_pack0(const float* __restrict__ W_ih0,
                                               const float* __restrict__ W_hh0,
                                               us_t* __restrict__ Wp) {
    int p = blockIdx.x * 256 + threadIdx.x;
    int r = p & 7, k = (p >> 3) & 1023, b = p >> 13;
    int gRow = ((r >> 1) & 3) * 512 + b * 2 + (r & 1);
    float v = (k < 512) ? W_ih0[(size_t)gRow * 1024 + 512 + k]
                        : W_hh0[(size_t)gRow * 512 + (k - 512)];
    Wp[p] = f2b(v);
}
__global__ __launch_bounds__(256) void k_pack1(const float* __restrict__ W_ih1,
                                               const float* __restrict__ W_hh1,
                                               us_t* __restrict__ Wp) {
    int p = blockIdx.x * 256 + threadIdx.x;
    int r = p & 7, k = (p >> 3) & 1023, b = p >> 13;
    int gRow = ((r >> 1) & 3) * 512 + b * 2 + (r & 1);
    float v = (k < 512) ? W_ih1[(size_t)gRow * 512 + k]
                        : W_hh1[(size_t)gRow * 512 + (k - 512)];
    Wp[p] = f2b(v);
}

// ---------------- W2 pre-pack (bf16, k-major): W2p[kb][v][j] = W2[v][kb*8+j], zero pad v>=4000 ----------------
__global__ __launch_bounds__(256) void k_packW2(const float* __restrict__ W2,
                                                us_t* __restrict__ W2p) {
    int p = blockIdx.x * 256 + threadIdx.x;    // 0..2097151 (64*4096*8)
    int j = p & 7, v = (p >> 3) & 4095, kb = p >> 15;
    float x = (v < V) ? W2[(size_t)v * 512 + kb * 8 + j] : 0.0f;
    W2p[p] = f2b(x);
}

// ---------------- X_pre GEMM, output TRANSPOSED [t][g][n] ----------------
__global__ __launch_bounds__(256) void k_xpre(const int* __restrict__ padded,
                                              const float* __restrict__ embedding,
                                              const float* __restrict__ W_ih0,
                                              const float* __restrict__ b_ih0,
                                              const float* __restrict__ b_hh0,
                                              float* __restrict__ Xpre) {
    __shared__ __align__(16) float At[32 * 33];
    __shared__ __align__(16) float Bt[32 * 68];
    __shared__ int toks[32];
    const int t = blockIdx.x, j0 = blockIdx.y * 64, tid = threadIdx.x;
    if (tid < 32) toks[tid] = (t == 0) ? 1 : padded[tid * 128 + (t - 1)];
    __syncthreads();
    const int ty = tid >> 4, tx = tid & 15;
    float acc[8];
#pragma unroll
    for (int i = 0; i < 8; ++i) acc[i] = 0.0f;
    for (int k0 = 0; k0 < 512; k0 += 32) {
        __syncthreads();
        {
            int r = tid >> 3, kk4 = tid & 7;
            float4 v = *(const float4*)(embedding + (size_t)toks[r] * 512 + k0 + kk4 * 4);
            At[(kk4 * 4 + 0) * 33 + r] = v.x;
            At[(kk4 * 4 + 1) * 33 + r] = v.y;
            At[(kk4 * 4 + 2) * 33 + r] = v.z;
            At[(kk4 * 4 + 3) * 33 + r] = v.w;
#pragma unroll
            for (int i2 = 0; i2 < 2; ++i2) {
                int f = tid + 256 * i2;
                int j = f >> 3, kb = f & 7;
                float4 w = *(const float4*)(W_ih0 + (size_t)(j0 + j) * 1024 + k0 + kb * 4);
                Bt[(kb * 4 + 0) * 68 + j] = w.x;
                Bt[(kb * 4 + 1) * 68 + j] = w.y;
                Bt[(kb * 4 + 2) * 68 + j] = w.z;
                Bt[(kb * 4 + 3) * 68 + j] = w.w;
            }
        }
        __syncthreads();
#pragma unroll
        for (int kk = 0; kk < 32; ++kk) {
            float a0 = At[kk * 33 + ty], a1 = At[kk * 33 + ty + 16];
            float4 b4 = *(const float4*)&Bt[kk * 68 + tx * 4];
            acc[0] += a0 * b4.x; acc[1] += a0 * b4.y; acc[2] += a0 * b4.z; acc[3] += a0 * b4.w;
            acc[4] += a1 * b4.x; acc[5] += a1 * b4.y; acc[6] += a1 * b4.z; acc[7] += a1 * b4.w;
        }
    }
    int j = j0 + tx * 4;
    float bi[4] = {b_ih0[j], b_ih0[j + 1], b_ih0[j + 2], b_ih0[j + 3]};
    float bh[4] = {b_hh0[j], b_hh0[j + 1], b_hh0[j + 2], b_hh0[j + 3]};
    float* base = Xpre + (size_t)t * 65536;
#pragma unroll
    for (int c = 0; c < 4; ++c) {
        base[(size_t)(j + c) * 32 + ty]      = acc[c]     + bi[c] + bh[c];
        base[(size_t)(j + c) * 32 + ty + 16] = acc[4 + c] + bi[c] + bh[c];
    }
}

// ---------------- staging helpers (into xl [256 k][35] f32) ----------------
__device__ __forceinline__ void stage_bf16_sub(const us_t* __restrict__ src,  // [256][32] bf16
                                               float* __restrict__ xl, int tid) {
    const uint2* g = (const uint2*)src;
#pragma unroll
    for (int j = 0; j < 8; ++j) {
        int f = j * 256 + tid;
        uint2 v = g[f];
        float* d = xl + (f >> 3) * 35 + (f & 7) * 4;
        d[0] = bfl(v.x); d[1] = bfh(v.x); d[2] = bfl(v.y); d[3] = bfh(v.y);
    }
}
__device__ __forceinline__ void stage_ctx_sub(const float* __restrict__ ctx,  // [32][512] f32, normalized
                                              int k0, float* __restrict__ xl, int tid) {
    const float4* g = (const float4*)ctx;
#pragma unroll
    for (int j = 0; j < 8; ++j) {
        int f = j * 256 + tid;
        int n = f >> 6, k4 = f & 63;
        float4 v = g[(size_t)n * 128 + (k0 >> 2) + k4];
        float* d = xl + (k4 * 4) * 35 + n;
        d[0]   = v.x;
        d[35]  = v.y;
        d[70]  = v.z;
        d[105] = v.w;
    }
}
__device__ __forceinline__ void compute_sub(const us_t* __restrict__ wp,  // LDS [256][8] bf16
                                            const float* __restrict__ xl,
                                            int q, int kq, float acc[8][4]) {
#pragma unroll
    for (int i = 0; i < 8; ++i) {
        int lk = kq + 32 * i;
        const float* xr = xl + lk * 35 + q * 4;
        float x0 = xr[0], x1 = xr[1], x2 = xr[2], x3 = xr[3];
        uint4 wv = *(const uint4*)(wp + (size_t)lk * 8);
        float wf[8] = {bfl(wv.x), bfh(wv.x), bfl(wv.y), bfh(wv.y),
                       bfl(wv.z), bfh(wv.z), bfl(wv.w), bfh(wv.w)};
#pragma unroll
        for (int r = 0; r < 8; ++r) {
            acc[r][0] += wf[r] * x0; acc[r][1] += wf[r] * x1;
            acc[r][2] += wf[r] * x2; acc[r][3] += wf[r] * x3;
        }
    }
}

// ---------------- gate reduction + nonlinearity + publish ----------------
__device__ __forceinline__ void lstm_tail(float acc[8][4],
                                          float g0, float g1, float g2, float g3,
                                          float& creg,
                                          u32* __restrict__ hOut32,
                                          u32* __restrict__ hT32,
                                          int b, int tid, int q, int kq,
                                          float* red, float* gv) {
#pragma unroll
    for (int c = 0; c < 2; ++c) {
        __syncthreads();
#pragma unroll
        for (int r = 0; r < 4; ++r)
#pragma unroll
            for (int s = 0; s < 4; ++s)
                red[r * 1056 + kq * 33 + q * 4 + s] = acc[c * 4 + r][s];
        __syncthreads();
        if (tid < 128) {
            int rr = tid >> 5, n = tid & 31;
            float g = 0.0f;
#pragma unroll
            for (int k2 = 0; k2 < 32; ++k2) g += red[rr * 1056 + k2 * 33 + n];
            gv[(c * 4 + rr) * 33 + n] = g;
        }
    }
    __syncthreads();
    if (tid < 64) {
        int jl = tid >> 5, nn = tid & 31;
        float gi = gv[(0 + jl) * 33 + nn] + g0;
        float gf = gv[(2 + jl) * 33 + nn] + g1;
        float gg = gv[(4 + jl) * 33 + nn] + g2;
        float go = gv[(6 + jl) * 33 + nn] + g3;
        int j = b * 2 + jl;
        float cn = sigmf(gf) * creg + sigmf(gi) * tanhf(gg);
        float hn = sigmf(go) * tanhf(cn);
        creg = cn;
        float hO = __shfl_xor(hn, 1);
        if ((nn & 1) == 0) {
            u32 pk = (u32)f2b(hn) | ((u32)f2b(hO) << 16);
            __hip_atomic_store(hOut32 + (j * 16 + (nn >> 1)), pk,
                               __ATOMIC_RELAXED, __HIP_MEMORY_SCOPE_AGENT);
        }
        if (hT32) {
            float hJ = __shfl_xor(hn, 32);
            if (jl == 0) {
                u32 pk = (u32)f2b(hn) | ((u32)f2b(hJ) << 16);
                __hip_atomic_store(hT32 + (nn * 260 + b), pk,
                                   __ATOMIC_RELAXED, __HIP_MEMORY_SCOPE_AGENT);
            }
        }
    }
}

// ---------------- cooperative sequential kernel ----------------
__global__ __launch_bounds__(256, 1) void k_seq(float* ws,
                                                const float* __restrict__ enc,
                                                const float* __restrict__ b_ih1,
                                                const float* __restrict__ b_hh1) {
    __shared__ __align__(16) us_t lds_w[16384];      // 32 KB both packs bf16
    __shared__ __align__(16) us_t lds_e[64 * 552];   // 69 KB enc slice bf16, skewed
    __shared__ __align__(16) float xl[256 * 35];     // 35.8 KB x tile / scratch
    __shared__ __align__(16) float gv[264];

    const int b = blockIdx.x, tid = threadIdx.x;
    const int q = tid >> 5, kq = tid & 31;
    float* red = xl;

    float* Xpre = ws + OFF_XPRE;
    us_t* h0b = (us_t*)(ws + OFF_H0B);
    us_t* h1b = (us_t*)(ws + OFF_H1B);
    u32*  h1T32 = (u32*)(ws + OFF_H1T);
    u32*  atb32 = (u32*)(ws + OFF_ATB);
    float* ctx = ws + OFF_CTX;
    u64*  mz  = (u64*)(ws + OFF_MZ);
    u32* flg = (u32*)(ws + OFF_FLG);

    float c0r = 0.0f, c1r = 0.0f;

    // hoisted P2 bias sums (constant across t)
    float bs0 = 0.f, bs1 = 0.f, bs2 = 0.f, bs3 = 0.f;
    if (tid < 64) {
        int j = b * 2 + (tid >> 5);
        bs0 = b_ih1[j] + b_hh1[j];
        bs1 = b_ih1[512 + j] + b_hh1[512 + j];
        bs2 = b_ih1[1024 + j] + b_hh1[1024 + j];
        bs3 = b_ih1[1536 + j] + b_hh1[1536 + j];
    }

    // ---- one-time LDS residency ----
    {
        const uint4* w0 = (const uint4*)((const us_t*)(ws + OFF_WP0) + (size_t)b * 8192);
        const uint4* w1 = (const uint4*)((const us_t*)(ws + OFF_WP1) + (size_t)b * 8192);
        for (int f = tid; f < 1024; f += 256) ((uint4*)lds_w)[f] = w0[f];
        for (int f = tid; f < 1024; f += 256) ((uint4*)(lds_w + 8192))[f] = w1[f];
        const int n = b >> 3, ts0 = (b & 7) * 64;
        const float4* encn = (const float4*)(enc + ((size_t)n * 512 + ts0) * 512);
#pragma unroll 4
        for (int j = 0; j < 32; ++j) {
            int f = tid + j * 256;
            int row = f >> 7, c4 = f & 127;
            float4 v = encn[(size_t)row * 128 + c4];
            ushort4 o;
            o.x = f2b(v.x); o.y = f2b(v.y); o.z = f2b(v.z); o.w = f2b(v.w);
            *(ushort4*)(lds_e + (size_t)row * 552 + (c4 >> 5) * 136 + (c4 & 31) * 4) = o;
        }
    }
    __syncthreads();

    for (int t = 0; t < T_STEPS; ++t) {
        const u32 base = 3u * t;
        // ============ P1: LSTM0, x = [attc(t) K0..511 | h0(t) K512..1023] ============
        // prefetch Xpre gate rows (no barrier dependency)
        float xg0 = 0.f, xg1 = 0.f, xg2 = 0.f, xg3 = 0.f;
        if (tid < 64) {
            const float* xp = Xpre + (size_t)t * 65536;
            int j = b * 2 + (tid >> 5), nn = tid & 31;
            xg0 = xp[(size_t)(0    + j) * 32 + nn];
            xg1 = xp[(size_t)(512  + j) * 32 + nn];
            xg2 = xp[(size_t)(1024 + j) * 32 + nn];
            xg3 = xp[(size_t)(1536 + j) * 32 + nn];
        }
        float acc[8][4];
#pragma unroll
        for (int r = 0; r < 8; ++r)
#pragma unroll
            for (int s = 0; s < 4; ++s) acc[r][s] = 0.0f;
        // early: h0(t) half (wp sub 2,3) — no barrier dependency
        {
            const us_t* h0s = h0b + (size_t)t * 16384;
#pragma unroll
            for (int s = 0; s < 2; ++s) {
                stage_bf16_sub(h0s + s * 8192, xl, tid);
                __syncthreads();
                compute_sub(lds_w + (2 + s) * 2048, xl, q, kq, acc);
                __syncthreads();
            }
        }
        wait_all(flg, base, tid);                  // attc(t) (normalized) ready
        {
            const float* ctxs = ctx + (size_t)t * 16384;
#pragma unroll
            for (int s = 0; s < 2; ++s) {
                stage_ctx_sub(ctxs, s * 256, xl, tid);
                __syncthreads();
                // write back bf16 attc rows owned by this block (for k_mlp)
                if (((2 * b) >> 8) == s && tid < 32) {
                    int r = 2 * b + (tid >> 4);
                    int rl = r & 255;
                    int n2 = (tid & 15) * 2;
                    u32 pk = (u32)f2b(xl[rl * 35 + n2]) | ((u32)f2b(xl[rl * 35 + n2 + 1]) << 16);
                    __hip_atomic_store(atb32 + ((size_t)t * 8192 + r * 16 + (tid & 15)), pk,
                                       __ATOMIC_RELAXED, __HIP_MEMORY_SCOPE_AGENT);
                }
                compute_sub(lds_w + s * 2048, xl, q, kq, acc);
                __syncthreads();
            }
        }
        lstm_tail(acc, xg0, xg1, xg2, xg3, c0r,
                  (u32*)(h0b + (size_t)(t + 1) * 16384), nullptr, b, tid, q, kq, red, gv);
        arrive(flg, b, tid, base + 1);
        // ============ P2: LSTM1, x = [h0(t+1) K0..511 | h1(t) K512..1023] ============
#pragma unroll
        for (int r = 0; r < 8; ++r)
#pragma unroll
            for (int s = 0; s < 4; ++s) acc[r][s] = 0.0f;
        {
            const us_t* h1s = h1b + (size_t)t * 16384;
#pragma unroll
            for (int s = 0; s < 2; ++s) {
                stage_bf16_sub(h1s + s * 8192, xl, tid);
                __syncthreads();
                compute_sub(lds_w + 8192 + (2 + s) * 2048, xl, q, kq, acc);
                __syncthreads();
            }
        }
        wait_all(flg, base + 1, tid);
        {
            const us_t* h0s = h0b + (size_t)(t + 1) * 16384;
#pragma unroll
            for (int s = 0; s < 2; ++s) {
                stage_bf16_sub(h0s + s * 8192, xl, tid);
                __syncthreads();
                compute_sub(lds_w + 8192 + s * 2048, xl, q, kq, acc);
                __syncthreads();
            }
        }
        lstm_tail(acc, bs0, bs1, bs2, bs3, c1r,
                  (u32*)(h1b + (size_t)(t + 1) * 16384), h1T32 + (size_t)(t + 1) * 8320,
                  b, tid, q, kq, red, gv);
        arrive(flg, b, tid, base + 2);
        // ============ ATTN: single-pass, 8 blocks/sample, mini-sync + normalized atomic ctx ============
        wait_all(flg, base + 2, tid);
        {
            const int n = b >> 3, c = b & 7;
            float* h_l = red;          // 512
            float* scp = red + 512;    // 256
            float* p_l = red + 768;    // 64
            {
                u32 hv = h1T32[(size_t)(t + 1) * 8320 + n * 260 + tid];
                float2 h2 = {bfl(hv), bfh(hv)};
                *(float2*)(h_l + tid * 2) = h2;
            }
            __syncthreads();
            {
                int ti = tid >> 2, kp = tid & 3;
                const us_t* er = lds_e + (size_t)ti * 552 + kp * 136;
                const float* hr = h_l + kp * 128;
                float s = 0.0f;
#pragma unroll
                for (int k8 = 0; k8 < 16; ++k8) {
                    uint4 u = *(const uint4*)(er + k8 * 8);
                    const float* h8 = hr + k8 * 8;
                    s += bfl(u.x) * h8[0] + bfh(u.x) * h8[1]
                       + bfl(u.y) * h8[2] + bfh(u.y) * h8[3]
                       + bfl(u.z) * h8[4] + bfh(u.z) * h8[5]
                       + bfl(u.w) * h8[6] + bfh(u.w) * h8[7];
                }
                scp[kp * 64 + ti] = s;
            }
            __syncthreads();
            if (tid < 64) {
                float sc = scp[tid] + scp[64 + tid] + scp[128 + tid] + scp[192 + tid];
                float m = sc;
                for (int o = 32; o; o >>= 1) m = fmaxf(m, __shfl_xor(m, o));
                float e = __expf(sc - m);
                float z = e;
                for (int o = 32; o; o >>= 1) z += __shfl_xor(z, o);
                p_l[tid] = e;
                if (tid == 0) {
                    red[840] = m;      // own chunk max
                    u64 pk = ((u64)__float_as_uint(m) << 32) | (u64)__float_as_uint(z);
                    __hip_atomic_store(mz + ((size_t)(t + 1) * 256 + n * 8 + c), pk,
                                       __ATOMIC_RELAXED, __HIP_MEMORY_SCOPE_AGENT);
                }
            }
            // mini-sync among the 8 chunk blocks of this sample -> global (M, Z)
            if (tid < 8) {
                u64 v;
                for (;;) {
                    v = __hip_atomic_load(mz + ((size_t)(t + 1) * 256 + n * 8 + tid),
                                          __ATOMIC_RELAXED, __HIP_MEMORY_SCOPE_AGENT);
                    if ((u32)v != 0u) break;
                    __builtin_amdgcn_s_sleep(1);
                }
                float mi = __uint_as_float((u32)(v >> 32));
                float zi = __uint_as_float((u32)v);
#pragma unroll
                for (int o = 1; o < 8; o <<= 1) {
                    float mo = __shfl_xor(mi, o);
                    float zo = __shfl_xor(zi, o);
                    float Mn = fmaxf(mi, mo);
                    zi = zi * __expf(mi - Mn) + zo * __expf(mo - Mn);
                    mi = Mn;
                }
                if (tid == 0)
                    red[841] = __expf(red[840] - mi) / zi;   // normalized scale for this chunk
            }
            __syncthreads();
            float scl = red[841];
            {
                int f0 = tid * 2;
                const us_t* eb = lds_e + (f0 >> 7) * 136 + (f0 & 127);
                float cv0 = 0.0f, cv1 = 0.0f;
#pragma unroll 8
                for (int ti = 0; ti < 64; ++ti) {
                    float w = p_l[ti];
                    u32 u = *(const u32*)(eb + (size_t)ti * 552);
                    cv0 += w * bfl(u); cv1 += w * bfh(u);
                }
                float* dst = ctx + (size_t)(t + 1) * 16384 + (size_t)n * 512 + f0;
                __hip_atomic_fetch_add(dst,     cv0 * scl, __ATOMIC_RELAXED, __HIP_MEMORY_SCOPE_AGENT);
                __hip_atomic_fetch_add(dst + 1, cv1 * scl, __ATOMIC_RELAXED, __HIP_MEMORY_SCOPE_AGENT);
            }
        }
        arrive(flg, b, tid, base + 3);
    }
    // tail: materialize bf16 attc(129) for k_mlp (ctx already normalized)
    wait_all(flg, 3u * T_STEPS, tid);
    if (b < 32) {
        int r = b * 16 + (tid >> 4);
        int n2 = (tid & 15) * 2;
        float v0 = ctx[(size_t)129 * 16384 + (size_t)n2 * 512 + r];
        float v1 = ctx[(size_t)129 * 16384 + (size_t)(n2 + 1) * 512 + r];
        u32 pk = (u32)f2b(v0) | ((u32)f2b(v1) << 16);
        __hip_atomic_store(atb32 + ((size_t)129 * 8192 + r * 16 + (tid & 15)), pk,
                           __ATOMIC_RELAXED, __HIP_MEMORY_SCOPE_AGENT);
    }
}

// ---------------- MLP hidden GEMM (bf16 in, bf16 out) ----------------
__global__ __launch_bounds__(256) void k_mlp(const us_t* __restrict__ h1b,
                                             const us_t* __restrict__ atb,
                                             const float* __restrict__ W1,
                                             const float* __restrict__ b1,
                                             us_t* __restrict__ hidb) {
    __shared__ __align__(16) float At[32 * 33];
    __shared__ __align__(16) float Bt[32 * 68];
    const int t = blockIdx.x, j0 = blockIdx.y * 64, tid = threadIdx.x;
    const int ty = tid >> 4, tx = tid & 15;
    float acc[8];
#pragma unroll
    for (int i = 0; i < 8; ++i) acc[i] = 0.0f;
    for (int k0 = 0; k0 < 1024; k0 += 32) {
        const us_t* src = (k0 < 512) ? (h1b + (size_t)(t + 1) * 16384 + (size_t)k0 * 32)
                                     : (atb + (size_t)t * 16384 + (size_t)(k0 - 512) * 32);
        __syncthreads();
        {
            int kk = tid >> 3, n4 = tid & 7;
            uint2 v = *(const uint2*)(src + (size_t)kk * 32 + n4 * 4);
            At[kk * 33 + n4 * 4 + 0] = bfl(v.x);
            At[kk * 33 + n4 * 4 + 1] = bfh(v.x);
            At[kk * 33 + n4 * 4 + 2] = bfl(v.y);
            At[kk * 33 + n4 * 4 + 3] = bfh(v.y);
#pragma unroll
            for (int i2 = 0; i2 < 2; ++i2) {
                int f = tid + 256 * i2;
                int j = f >> 3, kb = f & 7;
                float4 w = *(const float4*)(W1 + (size_t)(j0 + j) * 1024 + k0 + kb * 4);
                Bt[(kb * 4 + 0) * 68 + j] = w.x;
                Bt[(kb * 4 + 1) * 68 + j] = w.y;
                Bt[(kb * 4 + 2) * 68 + j] = w.z;
                Bt[(kb * 4 + 3) * 68 + j] = w.w;
            }
        }
        __syncthreads();
#pragma unroll
        for (int kk = 0; kk < 32; ++kk) {
            float a0 = At[kk * 33 + ty], a1 = At[kk * 33 + ty + 16];
            float4 b4 = *(const float4*)&Bt[kk * 68 + tx * 4];
            acc[0] += a0 * b4.x; acc[1] += a0 * b4.y; acc[2] += a0 * b4.z; acc[3] += a0 * b4.w;
            acc[4] += a1 * b4.x; acc[5] += a1 * b4.y; acc[6] += a1 * b4.z; acc[7] += a1 * b4.w;
        }
    }
    int j = j0 + tx * 4;
    float4 bv = *(const float4*)(b1 + j);
    int r0 = t * 32;
    ushort4 p0 = {f2b(tanhf(acc[0] + bv.x)), f2b(tanhf(acc[1] + bv.y)),
                  f2b(tanhf(acc[2] + bv.z)), f2b(tanhf(acc[3] + bv.w))};
    ushort4 p1 = {f2b(tanhf(acc[4] + bv.x)), f2b(tanhf(acc[5] + bv.y)),
                  f2b(tanhf(acc[6] + bv.z)), f2b(tanhf(acc[7] + bv.w))};
    *(ushort4*)(hidb + (size_t)(r0 + ty) * 512 + j) = p0;
    *(ushort4*)(hidb + (size_t)(r0 + ty + 16) * 512 + j) = p1;
}

// ---------------- MFMA logits + chunk logsumexp ----------------
// grid (129,16). Block: 32 samples x 256 vocab, K=512 bf16. A staged in LDS, B from packed W2p.
__global__ __launch_bounds__(256) void k_ce(const us_t* __restrict__ hidb,
                                            const us_t* __restrict__ W2p,
                                            const float* __restrict__ b2,
                                            const int* __restrict__ padded,
                                            float* __restrict__ cpm, float* __restrict__ cps,
                                            float* __restrict__ tgt) {
    __shared__ __align__(16) us_t Ash[32 * 520];
    __shared__ __align__(16) float lg[256 * 33];
    __shared__ float mred[8 * 32];
    __shared__ float Mf[32];
    __shared__ float sred[8 * 32];
    const int t = blockIdx.x, vc = blockIdx.y, tid = threadIdx.x;
    // stage A tile (rows t*32..+31) coalesced
    {
        const uint4* src = (const uint4*)(hidb + (size_t)t * 32 * 512);
#pragma unroll
        for (int i = 0; i < 8; ++i) {
            int f = tid + i * 256;            // row = f>>6, c = f&63 (uint4 = 8 bf16)
            uint4 v = src[f];
            *(uint4*)(Ash + (size_t)(f >> 6) * 520 + (f & 63) * 8) = v;
        }
    }
    __syncthreads();
    const int w = tid >> 6, lane = tid & 63;
    const int quad = lane >> 4, l16 = lane & 15;
    f32x4 acc[2][4];
#pragma unroll
    for (int mt = 0; mt < 2; ++mt)
#pragma unroll
        for (int nt = 0; nt < 4; ++nt)
#pragma unroll
            for (int r = 0; r < 4; ++r) acc[mt][nt][r] = 0.0f;
    const int vbase = vc * 256 + w * 64;
    for (int ks = 0; ks < 16; ++ks) {
        bf16x8 a0 = *(const bf16x8*)(Ash + (size_t)(l16)      * 520 + ks * 32 + quad * 8);
        bf16x8 a1 = *(const bf16x8*)(Ash + (size_t)(16 + l16) * 520 + ks * 32 + quad * 8);
        const us_t* bp = W2p + ((size_t)(ks * 4 + quad) * 4096 + vbase + l16) * 8;
#pragma unroll
        for (int nt = 0; nt < 4; ++nt) {
            bf16x8 bb = *(const bf16x8*)(bp + nt * 128);
            acc[0][nt] = __builtin_amdgcn_mfma_f32_16x16x32_bf16(a0, bb, acc[0][nt], 0, 0, 0);
            acc[1][nt] = __builtin_amdgcn_mfma_f32_16x16x32_bf16(a1, bb, acc[1][nt], 0, 0, 0);
        }
    }
    // epilogue: lg[vloc*33 + n] = logit + bias  (C layout: col=lane&15, row=quad*4+reg)
#pragma unroll
    for (int nt = 0; nt < 4; ++nt) {
        int vloc = w * 64 + nt * 16 + l16;
        int vglob = vc * 256 + vloc;
        float bias = (vglob < V) ? b2[vglob] : -1e30f;
#pragma unroll
        for (int mt = 0; mt < 2; ++mt)
#pragma unroll
            for (int r = 0; r < 4; ++r)
                lg[vloc * 33 + mt * 16 + quad * 4 + r] = acc[mt][nt][r] + bias;
    }
    __syncthreads();
    {
        int n = tid & 31, c = tid >> 5;
        float m = -1e30f;
        for (int i = 0; i < 32; ++i) m = fmaxf(m, lg[(c * 32 + i) * 33 + n]);
        mred[c * 32 + n] = m;
    }
    __syncthreads();
    if (tid < 32) {
        float M = mred[tid];
#pragma unroll
        for (int c = 1; c < 8; ++c) M = fmaxf(M, mred[c * 32 + tid]);
        Mf[tid] = M;
    }
    __syncthreads();
    {
        int n = tid & 31, c = tid >> 5;
        float M = Mf[n], s = 0.0f;
        for (int i = 0; i < 32; ++i) s += __expf(lg[(c * 32 + i) * 33 + n] - M);
        sred[c * 32 + n] = s;
    }
    __syncthreads();
    if (tid < 32) {
        int n = tid;
        float S = 0.0f;
#pragma unroll
        for (int c = 0; c < 8; ++c) S += sred[c * 32 + n];
        int r = t * 32 + n;
        cpm[(size_t)r * 16 + vc] = Mf[n];
        cps[(size_t)r * 16 + vc] = S;
        int vstar = (t < 128) ? padded[n * 128 + t] : 2;
        int vl = vstar - vc * 256;
        if (vl >= 0 && vl < 256) tgt[r] = lg[vl * 33 + n];
    }
}

// ---------------- final combine + CE reduction ----------------
__global__ __launch_bounds__(256) void k_final(const float* __restrict__ cpm,
                                               const float* __restrict__ cps,
                                               const float* __restrict__ tgt,
                                               float* __restrict__ out) {
    __shared__ float red[256];
    float local = 0.0f;
    for (int r = threadIdx.x; r < 4128; r += 256) {
        float M = -1e30f;
#pragma unroll
        for (int c = 0; c < 16; ++c) M = fmaxf(M, cpm[(size_t)r * 16 + c]);
        float S = 0.0f;
#pragma unroll
        for (int c = 0; c < 16; ++c) S += cps[(size_t)r * 16 + c] * __expf(cpm[(size_t)r * 16 + c] - M);
        local += (M + logf(S)) - tgt[r];
    }
    red[threadIdx.x] = local;
    __syncthreads();
    for (int o = 128; o; o >>= 1) {
        if (threadIdx.x < o) red[threadIdx.x] += red[threadIdx.x + o];
        __syncthreads();
    }
    if (threadIdx.x == 0) out[0] = red[0] * (128.0f / 4128.0f);
}

extern "C" void kernel_launch(void* const* d_in, const int* in_sizes, int n_in,
                              void* d_out, int out_size, void* d_ws, size_t ws_size,
                              hipStream_t stream) {
    const int*   padded = (const int*)d_in[0];
    const float* enc    = (const float*)d_in[1];
    const float* emb    = (const float*)d_in[2];
    const float* W_ih0  = (const float*)d_in[3];
    const float* b_ih0  = (const float*)d_in[4];
    const float* W_hh0  = (const float*)d_in[5];
    const float* b_hh0  = (const float*)d_in[6];
    const float* W_ih1  = (const float*)d_in[7];
    const float* b_ih1  = (const float*)d_in[8];
    const float* W_hh1  = (const float*)d_in[9];
    const float* b_hh1  = (const float*)d_in[10];
    const float* W1     = (const float*)d_in[11];
    const float* b1     = (const float*)d_in[12];
    const float* W2     = (const float*)d_in[13];
    const float* b2     = (const float*)d_in[14];
    float* ws  = (float*)d_ws;
    float* out = (float*)d_out;

    hipLaunchKernelGGL(k_init, dim3(640), dim3(256), 0, stream, ws);
    hipLaunchKernelGGL(k_pack0, dim3(8192), dim3(256), 0, stream,
                       W_ih0, W_hh0, (us_t*)(ws + OFF_WP0));
    hipLaunchKernelGGL(k_pack1, dim3(8192), dim3(256), 0, stream,
                       W_ih1, W_hh1, (us_t*)(ws + OFF_WP1));
    hipLaunchKernelGGL(k_packW2, dim3(8192), dim3(256), 0, stream,
                       W2, (us_t*)(ws + OFF_W2P));
    hipLaunchKernelGGL(k_xpre, dim3(129, 32), dim3(256), 0, stream,
                       padded, emb, W_ih0, b_ih0, b_hh0, ws + OFF_XPRE);
    {
        float* ws_a = ws;
        const float* enc_a = enc;
        const float* bia = b_ih1;
        const float* bib = b_hh1;
        void* args[] = {(void*)&ws_a, (void*)&enc_a, (void*)&bia, (void*)&bib};
        hipLaunchCooperativeKernel((void*)k_seq, dim3(256), dim3(256), args, 0, stream);
    }
    hipLaunchKernelGGL(k_mlp, dim3(129, 8), dim3(256), 0, stream,
                       (const us_t*)(ws + OFF_H1B), (const us_t*)(ws + OFF_ATB), W1, b1,
                       (us_t*)(ws + OFF_HID));
    hipLaunchKernelGGL(k_ce, dim3(129, 16), dim3(256), 0, stream,
                       (const us_t*)(ws + OFF_HID), (const us_t*)(ws + OFF_W2P), b2, padded,
                       ws + OFF_CPM, ws + OFF_CPS, ws + OFF_TGT);
    hipLaunchKernelGGL(k_final, dim3(1), dim3(256), 0, stream,
                       ws + OFF_CPM, ws + OFF_CPS, ws + OFF_TGT, out);
}